// Round 12
// baseline (833.611 us; speedup 1.0000x reference)
//
#include <hip/hip_runtime.h>
#include <hip/hip_bf16.h>

// Model: 4-layer Mamba2 TS model. B=32 L=1024 DM=256 DI=512 DST=64 NH=8 HD=64
// DC=4 Q=64 chunks=16 DIP=1160(pad 1280) CONVD=640 PRED=192 CO=21.
// I/O fp32. bf16 MFMA operands, fp32 accum. WS ~236.5 MB.
// R29->R30: SSD p-split (grid 1024->2048): each (bh,grp) -> 2 blocks for
// p-halves. stateA4 splits perfectly (MFMA 8->4/chunk, no dup; LDS 13.3KB).
// outBC4: Xt/Shi/Slo halve, mm1 duplicated (+8) but mm2+state halve (-16);
// LDS 53.8->40.2KB -> 4 blocks/CU (was 3), work depth 4->8 blocks/CU ->
// latency hiding ~2x where kernel sits at MfmaUtil 8.5%/Occ 16%. Numerics
// bit-identical (same MFMAs, per-t accs distributed; acbuf dup-written with
// identical values). Ledger: BK=64 GEMM plateau; pipelined dbuf bad;
// dt-in-wave fusion bad; generic XCD swizzle bad; gate-in-outBC4 bad (R23);
// conv-in-ip bad (R25); NT stores/loads bad (R27/R28); R19 og fusion good;
// R20 SSD prefetch good; R21 ip XCD-affinity + scan-fold good; R26 SSD
// bank-swizzle good. Baseline R26/R29: 737-746us (noise +-5-9).

typedef unsigned short ushort_t;
typedef unsigned int uint_t;
typedef __attribute__((ext_vector_type(8))) short short8;
typedef __attribute__((ext_vector_type(4))) float f32x4;
typedef __attribute__((ext_vector_type(4))) ushort_t ushort4_t;

__device__ __forceinline__ float b2f(ushort_t u) {
    uint_t v = ((uint_t)u) << 16;
    return __builtin_bit_cast(float, v);
}
__device__ __forceinline__ ushort_t f2b(float f) {
    uint_t u = __builtin_bit_cast(uint_t, f);
    uint_t r = (u + 0x7FFFu + ((u >> 16) & 1u)) >> 16;
    return (ushort_t)r;
}
// HW packed convert: dst.lo = bf16(a), dst.hi = bf16(b), RNE (== f2b)
__device__ __forceinline__ uint_t cvt_pk2(float a, float b) {
    uint_t r;
    asm("v_cvt_pk_bf16_f32 %0, %1, %2" : "=v"(r) : "v"(a), "v"(b));
    return r;
}
__device__ __forceinline__ float silu_f(float x) {
    return x / (1.f + __expf(-x));
}
__device__ __forceinline__ void gl_lds16(const ushort_t* g, ushort_t* l) {
    __builtin_amdgcn_global_load_lds(
        (const __attribute__((address_space(1))) unsigned int*)g,
        (__attribute__((address_space(3))) unsigned int*)l, 16, 0, 0);
}
// LDS col swizzle for [.][68] tiles: breaks 16-row-step bank aliasing.
__device__ __forceinline__ int xsw(int row) {
    return (((row >> 4) ^ row) & 3) << 3;
}

// ---------------- weight converts ----------------
// in_proj w: [4][1160][256] -> bf16 [4][1280][256], rows >=1160 zero
__global__ __launch_bounds__(256) void cvt_pad_ip(const float* __restrict__ in,
        ushort_t* __restrict__ out) {
    int i = blockIdx.x * 256 + threadIdx.x;     // < 4*1280*256
    if (i >= 4 * 1280 * 256) return;
    int layer = i / (1280 * 256);
    int rem = i - layer * 1280 * 256;
    int n = rem >> 8, k = rem & 255;
    out[i] = (n < 1160) ? f2b(in[(size_t)layer * 1160 * 256 + n * 256 + k]) : (ushort_t)0;
}
// out_proj w: [4][256][512] * gw[4][512] (col of K axis) -> bf16 W' fold
__global__ __launch_bounds__(256) void cvt_wop(const float* __restrict__ in,
        const float* __restrict__ gw, ushort_t* __restrict__ out) {
    int i = blockIdx.x * 256 + threadIdx.x;     // < 524288 exactly
    int layer = i >> 17;
    int c = i & 511;
    out[i] = f2b(in[i] * gw[layer * 512 + c]);
}
// conv w: [4][640][4] -> [4][4][640] fp32 transpose
__global__ __launch_bounds__(256) void cvt_convw(const float* __restrict__ in,
        float* __restrict__ out) {
    int i = blockIdx.x * 256 + threadIdx.x;     // < 4*2560
    if (i >= 10240) return;
    int layer = i / 2560;
    int rem = i - layer * 2560;
    int k = rem / 640, ch = rem - k * 640;
    out[i] = in[layer * 2560 + ch * 4 + k];
}

// ---------------- pos-emb table: pe[l][d], computed once ----------------
__global__ __launch_bounds__(256) void pe_kernel(float* __restrict__ pe) {
    int l = blockIdx.x, d = threadIdx.x;
    float div = __expf((float)(d & ~1) * (-9.210340371976184f / 256.0f));
    float arg = (float)l * div;
    pe[l * 256 + d] = (d & 1) ? cosf(arg) : sinf(arg);
}

// ---------------- stats ----------------
__global__ __launch_bounds__(256) void stats_kernel(const float* __restrict__ xe,
        float* __restrict__ meanb, float* __restrict__ stdb, float* __restrict__ rstdb) {
    int bi = blockIdx.x;
    int b = bi / 21, c = bi - b * 21;
    int tid = threadIdx.x;
    float s = 0.f, s2 = 0.f;
    for (int l = tid; l < 1024; l += 256) {
        float v = xe[(b * 1024 + l) * 21 + c];
        s += v; s2 += v * v;
    }
    __shared__ float r1[4], r2[4];
    for (int o = 32; o > 0; o >>= 1) { s += __shfl_down(s, o, 64); s2 += __shfl_down(s2, o, 64); }
    if ((tid & 63) == 0) { r1[tid >> 6] = s; r2[tid >> 6] = s2; }
    __syncthreads();
    if (tid == 0) {
        float S = r1[0] + r1[1] + r1[2] + r1[3];
        float S2 = r2[0] + r2[1] + r2[2] + r2[3];
        float m = S * (1.f / 1024.f);
        float var = S2 * (1.f / 1024.f) - m * m;
        float sd = sqrtf(var + 1e-5f);
        meanb[bi] = m; stdb[bi] = sd; rstdb[bi] = 1.f / sd;
    }
}

// ---------------- embedding: sliding-window, tokw in registers ----------------
__global__ __launch_bounds__(256) void embed3_kernel(const float* __restrict__ xe,
        const float* __restrict__ xm, const float* __restrict__ tokw,
        const float* __restrict__ tembw, const float* __restrict__ pe,
        const float* __restrict__ meanb, const float* __restrict__ rstdb,
        float* __restrict__ h, ushort_t* __restrict__ hbf) {
    int blk = blockIdx.x;               // b*16 + tile
    int b = blk >> 4, t = blk & 15;
    int l0 = t * 64;
    int tid = threadIdx.x;              // = d
    __shared__ float xw[66][22];        // normalized x window, row0 = l0-1 (wrap)
    __shared__ float xmw[64][4];
    __shared__ float mn[21], rs[21];
    if (tid < 21) { mn[tid] = meanb[b * 21 + tid]; rs[tid] = rstdb[b * 21 + tid]; }
    float twr[63];
    {
        const float* tp = tokw + tid * 63;
        #pragma unroll
        for (int i = 0; i < 63; i++) twr[i] = tp[i];
    }
    float tbr[4];
    #pragma unroll
    for (int k = 0; k < 4; k++) tbr[k] = tembw[tid * 4 + k];
    __syncthreads();
    for (int i = tid; i < 1386; i += 256) {
        int row = i / 21, c = i - row * 21;
        int gl = (l0 - 1 + row + 1024) & 1023;
        xw[row][c] = (xe[(size_t)(b * 1024 + gl) * 21 + c] - mn[c]) * rs[c];
    }
    {
        int row = tid >> 2, c = tid & 3;
        xmw[row][c] = xm[(size_t)(b * 1024 + l0 + row) * 4 + c];
    }
    __syncthreads();
    int d = tid;
    float acc2 = 0.f, acc1 = 0.f;   // pending partial sums for out[r-2], out[r-1]
    for (int r = 0; r < 66; r++) {
        float s0 = 0.f, s1 = 0.f, s2 = 0.f;
        #pragma unroll
        for (int c = 0; c < 21; c++) {
            float xv = xw[r][c];
            s0 += xv * twr[c * 3 + 0];
            s1 += xv * twr[c * 3 + 1];
            s2 += xv * twr[c * 3 + 2];
        }
        if (r >= 2) {
            int li = r - 2;
            float acc = acc2 + s2 + pe[(size_t)(l0 + li) * 256 + d];
            #pragma unroll
            for (int k = 0; k < 4; k++) acc += xmw[li][k] * tbr[k];
            size_t o = (size_t)(b * 1024 + l0 + li) * 256 + d;
            h[o] = acc;
            hbf[o] = f2b(acc);
        }
        acc2 = acc1 + s1;
        acc1 = s0;
    }
}

// ---------------- 128x128 LDS-staged GEMM mainloop, BK=64 (2x32 panels) ----------------
template<int KDIM>
__device__ __forceinline__ void gemm128_main(const ushort_t* __restrict__ Ab,
        const ushort_t* __restrict__ Wb, ushort_t* sA, ushort_t* sW,
        f32x4 (&acc)[16], int m0, int n0) {
    int tid = threadIdx.x;
    int w = tid >> 6, lane = tid & 63;
    int wm = w >> 1, wn = w & 1;
    int rr = lane & 15, quad = lane >> 4;
    int srow0 = w * 32 + (lane >> 2);       // staging row (+ j*16)
    int skk = (lane & 3) * 8;               // staging k-offset (shorts)
    int sl0 = w * 1024 + lane * 8;          // staging LDS index (+ j*512, + p*4096)
    for (int k0 = 0; k0 < KDIM; k0 += 64) {
        __syncthreads();                    // prev MFMA reads done before overwrite
        #pragma unroll
        for (int p = 0; p < 2; p++) {
            #pragma unroll
            for (int j = 0; j < 2; j++) {
                int row = srow0 + j * 16;
                int koff = k0 + p * 32 + skk;
                gl_lds16(Ab + (size_t)(m0 + row) * KDIM + koff, &sA[p * 4096 + sl0 + j * 512]);
                gl_lds16(Wb + (size_t)(n0 + row) * KDIM + koff, &sW[p * 4096 + sl0 + j * 512]);
            }
        }
        __syncthreads();                    // compiler drains vmcnt before barrier
        #pragma unroll
        for (int p = 0; p < 2; p++) {
            short8 a[4], b[4];
            #pragma unroll
            for (int i = 0; i < 4; i++)
                a[i] = *(const short8*)&sA[p * 4096 + (wm * 64 + i * 16 + rr) * 32 + quad * 8];
            #pragma unroll
            for (int j = 0; j < 4; j++)
                b[j] = *(const short8*)&sW[p * 4096 + (wn * 64 + j * 16 + rr) * 32 + quad * 8];
            #pragma unroll
            for (int i = 0; i < 4; i++)
                #pragma unroll
                for (int j = 0; j < 4; j++)
                    acc[i * 4 + j] = __builtin_amdgcn_mfma_f32_16x16x32_bf16(a[i], b[j], acc[i * 4 + j], 0, 0, 0);
        }
    }
}

// in_proj: A[32768x256] x W[1280x256] -> split z (n<512) | xBC/dt (512<=n<1160)
// XCD-affinity map: the 10 blocks sharing an A m-tile run consecutively on one
// XCD (round-robin blk%8) -> A tile fetched from HBM once, then L2-hits.
__global__ __launch_bounds__(256) void gemm_ip(const ushort_t* __restrict__ A,
        const ushort_t* __restrict__ W, ushort_t* __restrict__ zbuf,
        ushort_t* __restrict__ xbuf) {
    int g = blockIdx.x;                 // 2560
    int xcd = g & 7, s = g >> 3;        // per-XCD sequence 0..319
    int sq = s / 10;                    // 0..31
    int tn = s - sq * 10;               // 0..9
    int tm = (sq << 3) | xcd;           // 0..255, tm%8 == xcd
    int m0 = tm * 128, n0 = tn * 128;
    __shared__ ushort_t sA[8192], sW[8192];
    f32x4 acc[16];
    #pragma unroll
    for (int i = 0; i < 16; i++) acc[i] = (f32x4){0.f, 0.f, 0.f, 0.f};
    gemm128_main<256>(A, W, sA, sW, acc, m0, n0);
    int lane = threadIdx.x & 63, w = threadIdx.x >> 6;
    int wm = w >> 1, wn = w & 1;
    int rr = lane & 15, quad = lane >> 4;
    #pragma unroll
    for (int i = 0; i < 4; i++) {
        int mrow = m0 + wm * 64 + i * 16 + quad * 4;
        #pragma unroll
        for (int j = 0; j < 4; j++) {
            int n = n0 + wn * 64 + j * 16 + rr;
            uint_t u01 = cvt_pk2(acc[i * 4 + j][0], acc[i * 4 + j][1]);
            uint_t u23 = cvt_pk2(acc[i * 4 + j][2], acc[i * 4 + j][3]);
            ushort_t vs[4] = {(ushort_t)u01, (ushort_t)(u01 >> 16),
                              (ushort_t)u23, (ushort_t)(u23 >> 16)};
            #pragma unroll
            for (int r2 = 0; r2 < 4; r2++) {
                if (n < 512) zbuf[(size_t)(mrow + r2) * 512 + n] = vs[r2];
                else if (n < 1160) xbuf[(size_t)(mrow + r2) * 704 + (n - 512)] = vs[r2];
            }
        }
    }
}

// ---------------- fused out_proj: gate(A) x W'[256x512] + residual + LN ----------------
// A = y*silu(z) bf16 (un-normalized); rms = rsqrt(mean g^2) applied POST-matmul
// (gw folded into W'). M-tile 32 -> 1024 blocks (4/CU), gate in reg-staging
// (8 elems/thread/k-step), ssq via 8-lane shfl groups; LN in epilogue.
__global__ __launch_bounds__(256) void gemm_og(const ushort_t* __restrict__ Yb,
        const ushort_t* __restrict__ Zb, const ushort_t* __restrict__ Wb,
        float* __restrict__ h, ushort_t* __restrict__ hbf,
        const float* __restrict__ lng, const float* __restrict__ lnb) {
    int m0 = blockIdx.x * 32;
    int tid = threadIdx.x;
    int w = tid >> 6, lane = tid & 63;
    int wm = w >> 1, wn = w & 1;
    int rr = lane & 15, quad = lane >> 4;
    __shared__ ushort_t sA[2048];           // [p][32][32] shorts = 4KB
    __shared__ ushort_t sW[16384];          // [p][256][32] shorts = 32KB
    __shared__ float gssq[32];
    __shared__ float rsum[32][2], rssq[32][2];

    // A gate-staging: 8 elems/thread. row = tid>>3 (0..31), kk = (tid&7)*8
    int arow = tid >> 3;
    int akk = (tid & 7) * 8;
    const ushort_t* yrow = Yb + (size_t)(m0 + arow) * 512 + akk;
    const ushort_t* zrow = Zb + (size_t)(m0 + arow) * 512 + akk;
    // ds dest: panel p = (tid&7)>>2, in-panel k = (tid&3)*8
    ushort_t* adst = &sA[((tid & 7) >> 2) * 1024 + arow * 32 + (tid & 3) * 8];

    f32x4 acc[8];
    #pragma unroll
    for (int j = 0; j < 8; j++) acc[j] = (f32x4){0.f, 0.f, 0.f, 0.f};
    float ssqr = 0.f;

    short8 y0 = *(const short8*)(yrow);
    short8 z0 = *(const short8*)(zrow);

    for (int k0 = 0; k0 < 512; k0 += 64) {
        __syncthreads();                    // prev MFMA reads done before overwrite
        // gate in registers -> ds_write A (cvt_pk pairs)
        short8 ga;
        {
            uint_t* gau = (uint_t*)&ga;
            #pragma unroll
            for (int jj = 0; jj < 8; jj += 2) {
                float g0 = b2f(((ushort_t*)&y0)[jj]) * silu_f(b2f(((ushort_t*)&z0)[jj]));
                float g1 = b2f(((ushort_t*)&y0)[jj + 1]) * silu_f(b2f(((ushort_t*)&z0)[jj + 1]));
                ssqr += g0 * g0 + g1 * g1;
                gau[jj >> 1] = cvt_pk2(g0, g1);
            }
        }
        *(short8*)adst = ga;
        // prefetch next k-step's y/z (drains with W's gl_lds at the barrier)
        if (k0 + 64 < 512) {
            y0 = *(const short8*)(yrow + k0 + 64);
            z0 = *(const short8*)(zrow + k0 + 64);
        }
        // W' staging: 256 rows x 64 k via global_load_lds
        #pragma unroll
        for (int p = 0; p < 2; p++) {
            #pragma unroll
            for (int j = 0; j < 4; j++)
                gl_lds16(Wb + (size_t)(w * 64 + j * 16 + (lane >> 2)) * 512
                             + k0 + p * 32 + (lane & 3) * 8,
                         &sW[p * 8192 + w * 2048 + j * 512 + lane * 8]);
        }
        __syncthreads();                    // drains lgkm (ds_write) + vm (gl_lds)
        #pragma unroll
        for (int p = 0; p < 2; p++) {
            short8 a = *(const short8*)&sA[p * 1024 + (wm * 16 + rr) * 32 + quad * 8];
            #pragma unroll
            for (int j = 0; j < 8; j++) {
                short8 bv = *(const short8*)&sW[p * 8192 + (wn * 128 + j * 16 + rr) * 32 + quad * 8];
                acc[j] = __builtin_amdgcn_mfma_f32_16x16x32_bf16(a, bv, acc[j], 0, 0, 0);
            }
        }
    }

    // row sum(g^2): reduce across the 8 lanes sharing a row (contiguous lanes)
    ssqr += __shfl_xor(ssqr, 1, 64);
    ssqr += __shfl_xor(ssqr, 2, 64);
    ssqr += __shfl_xor(ssqr, 4, 64);
    if ((tid & 7) == 0) gssq[arow] = ssqr;
    __syncthreads();

    float gl[8], bl[8];
    #pragma unroll
    for (int j = 0; j < 8; j++) {
        int col = wn * 128 + j * 16 + rr;
        gl[j] = lng[col]; bl[j] = lnb[col];
    }
    // pass 1: x = h + rms*acc; accumulate row stats
    #pragma unroll
    for (int r2 = 0; r2 < 4; r2++) {
        int rowl = wm * 16 + quad * 4 + r2;
        float rmsv = rsqrtf(gssq[rowl] * (1.f / 512.f) + 1e-5f);
        size_t gbase = (size_t)(m0 + rowl) * 256;
        float s = 0.f, s2 = 0.f;
        #pragma unroll
        for (int j = 0; j < 8; j++) {
            int col = wn * 128 + j * 16 + rr;
            float xv = h[gbase + col] + acc[j][r2] * rmsv;
            acc[j][r2] = xv;
            s += xv; s2 += xv * xv;
        }
        #pragma unroll
        for (int o = 1; o < 16; o <<= 1) {
            s += __shfl_xor(s, o, 64);
            s2 += __shfl_xor(s2, o, 64);
        }
        if (rr == 0) { rsum[rowl][wn] = s; rssq[rowl][wn] = s2; }
    }
    __syncthreads();
    // pass 2: LN + write h (fp32) and hbf (bf16)
    #pragma unroll
    for (int r2 = 0; r2 < 4; r2++) {
        int rowl = wm * 16 + quad * 4 + r2;
        float S = rsum[rowl][0] + rsum[rowl][1];
        float S2 = rssq[rowl][0] + rssq[rowl][1];
        float mu = S * (1.f / 256.f);
        float var = S2 * (1.f / 256.f) - mu * mu;
        float rstd = rsqrtf(var + 1e-5f);
        size_t gbase = (size_t)(m0 + rowl) * 256;
        #pragma unroll
        for (int j = 0; j < 8; j++) {
            int col = wn * 128 + j * 16 + rr;
            float o = (acc[j][r2] - mu) * rstd * gl[j] + bl[j];
            h[gbase + col] = o;
            hbf[gbase + col] = f2b(o);
        }
    }
}

// ---------------- conv (blocks < 2560) + dt (blocks >= 2560, block-uniform) ----------------
__global__ __launch_bounds__(256) void conv_kernel(const ushort_t* __restrict__ xbuf,
        const float* __restrict__ cwt, const float* __restrict__ cb,
        const float* __restrict__ dtb, ushort_t* __restrict__ xc,
        float* __restrict__ dts) {
    if (blockIdx.x >= 2560) {
        int r = (blockIdx.x - 2560) * 256 + threadIdx.x;
        short8 dv = *(const short8*)(xbuf + (size_t)r * 704 + 640);
        #pragma unroll
        for (int j = 0; j < 8; j++) {
            float x = b2f(((ushort_t*)&dv)[j]) + dtb[j];
            dts[(size_t)r * 8 + j] = (x > 20.f) ? x : log1pf(__expf(x));
        }
        return;
    }
    int idx = blockIdx.x * 256 + threadIdx.x;   // < 8192*80
    int g = idx % 80;
    int rt = idx / 80;
    int ch0 = g * 8;
    int b = rt >> 8;
    int l0 = (rt & 255) << 2;
    float wgt[4][8];
    #pragma unroll
    for (int k = 0; k < 4; k++) {
        float4 w0 = *(const float4*)(cwt + k * 640 + ch0);
        float4 w1 = *(const float4*)(cwt + k * 640 + ch0 + 4);
        wgt[k][0] = w0.x; wgt[k][1] = w0.y; wgt[k][2] = w0.z; wgt[k][3] = w0.w;
        wgt[k][4] = w1.x; wgt[k][5] = w1.y; wgt[k][6] = w1.z; wgt[k][7] = w1.w;
    }
    float bias[8];
    {
        float4 b0 = *(const float4*)(cb + ch0);
        float4 b1 = *(const float4*)(cb + ch0 + 4);
        bias[0] = b0.x; bias[1] = b0.y; bias[2] = b0.z; bias[3] = b0.w;
        bias[4] = b1.x; bias[5] = b1.y; bias[6] = b1.z; bias[7] = b1.w;
    }
    short8 xr[7];
    const ushort_t* base = xbuf + (size_t)(b * 1024 + l0) * 704 + ch0;
    #pragma unroll
    for (int i = 0; i < 7; i++) {
        int ll = l0 - 3 + i;
        if (ll >= 0) xr[i] = *(const short8*)(base + (ptrdiff_t)(i - 3) * 704);
        else         xr[i] = (short8){0, 0, 0, 0, 0, 0, 0, 0};
    }
    #pragma unroll
    for (int lo = 0; lo < 4; lo++) {
        float acc[8];
        #pragma unroll
        for (int j = 0; j < 8; j++) acc[j] = bias[j];
        #pragma unroll
        for (int k = 0; k < 4; k++) {
            #pragma unroll
            for (int j = 0; j < 8; j++)
                acc[j] += b2f(((ushort_t*)&xr[lo + k])[j]) * wgt[k][j];
        }
        short8 o;
        #pragma unroll
        for (int j = 0; j < 8; j++) ((ushort_t*)&o)[j] = f2b(silu_f(acc[j]));
        *(short8*)(xc + (size_t)(b * 1024 + l0 + lo) * 640 + ch0) = o;
    }
}

// ---------------- SSD A4 (p-split): partial states per (b,h,grp,p-half) ----------------
// T = ad_c*T + (B*dec)^T@X per chunk (p-half only); MFMA 4/chunk (was 8).
// acbuf written duplicated by both p-halves (identical values, benign).
__global__ __launch_bounds__(256) void ssd_stateA4(const ushort_t* __restrict__ xc,
        const float* __restrict__ dts, const float* __restrict__ alog,
        float* __restrict__ stbuf, float* __restrict__ acbuf) {
    int idx = blockIdx.x;               // 2048 = bh*8 + grp*2 + ph
    int bh = idx >> 3, grp = (idx >> 1) & 3, ph = idx & 1;
    int b = bh >> 3, h = bh & 7;
    float Ah = -__expf(alog[h]);
    int tid = threadIdx.x;
    int q = tid >> 2, pb = (tid & 3) * 16;  // B loader (64 n-cols)
    int px = (tid & 3) * 8;                 // X loader (32 p-cols of this half)
    int w = tid >> 6, lane = tid & 63;
    int rr = lane & 15, quad = lane >> 4, qb = w * 16;

    __shared__ ushort_t Bt[64][68], Xt[32][68];
    __shared__ float dec_s[64];
    __shared__ float ad_sh;

    float T[2][4];
    #pragma unroll
    for (int t = 0; t < 2; t++)
        #pragma unroll
        for (int r2 = 0; r2 < 4; r2++) T[t][r2] = 0.f;

    // prefetch chunk grp*4
    ushort_t bv[16], xv[8];
    float d_pf = 0.f;
    {
        int chunk = grp * 4;
        int l0 = chunk * 64;
        const ushort_t* xrow = xc + (size_t)(b * 1024 + l0 + q) * 640;
        *(short8*)&bv[0] = *(const short8*)(xrow + 512 + pb);
        *(short8*)&bv[8] = *(const short8*)(xrow + 512 + pb + 8);
        *(short8*)&xv[0] = *(const short8*)(xrow + h * 64 + ph * 32 + px);
        if (tid < 64)
            d_pf = dts[(size_t)(b * 1024 + l0 + tid) * 8 + h];
    }

    for (int c4 = 0; c4 < 4; c4++) {
        int chunk = grp * 4 + c4;
        size_t cidx = (size_t)bh * 16 + chunk;
        // P0: Xt transpose write + wave0 scalars (all from prefetched regs)
        #pragma unroll
        for (int j = 0; j < 8; j++) Xt[px + j][q ^ xsw(px + j)] = xv[j];
        if (tid < 64) {
            float d = d_pf;
            float a = d * Ah;
            #pragma unroll
            for (int off = 1; off < 64; off <<= 1) {
                float t = __shfl_up(a, off, 64);
                if (tid >= off) a += t;
            }
            acbuf[cidx * 64 + tid] = a;     // duplicated across ph, identical
            float tot = __shfl(a, 63, 64);
            dec_s[tid] = __expf(tot - a) * d;
            if (tid == 0) ad_sh = __expf(tot);
        }
        __syncthreads();    // b1: Xt + dec_s + ad_sh ready
        // P1: Bt from current bv (cvt_pk pairs), then prefetch next chunk
        {
            float dq = dec_s[q];
            #pragma unroll
            for (int j = 0; j < 16; j += 2) {
                uint_t u = cvt_pk2(b2f(bv[j]) * dq, b2f(bv[j + 1]) * dq);
                Bt[pb + j][q ^ xsw(pb + j)] = (ushort_t)u;
                Bt[pb + j + 1][q ^ xsw(pb + j + 1)] = (ushort_t)(u >> 16);
            }
        }
        if (c4 < 3) {
            int l0n = (chunk + 1) * 64;
            const ushort_t* xrow = xc + (size_t)(b * 1024 + l0n + q) * 640;
            *(short8*)&bv[0] = *(const short8*)(xrow + 512 + pb);
            *(short8*)&bv[8] = *(const short8*)(xrow + 512 + pb + 8);
            *(short8*)&xv[0] = *(const short8*)(xrow + h * 64 + ph * 32 + px);
            if (tid < 64)
                d_pf = dts[(size_t)(b * 1024 + l0n + tid) * 8 + h];
        }
        __syncthreads();    // b2: Bt ready
        // P2: MFMA + T update (p-half)
        f32x4 acc[2];
        #pragma unroll
        for (int t = 0; t < 2; t++) acc[t] = (f32x4){0.f, 0.f, 0.f, 0.f};
        #pragma unroll
        for (int ks = 0; ks < 2; ks++) {
            short8 a = *(const short8*)(&Bt[qb + rr][(ks * 32 + quad * 8) ^ xsw(qb + rr)]);
            #pragma unroll
            for (int t = 0; t < 2; t++) {
                short8 bb = *(const short8*)(&Xt[t * 16 + rr][(ks * 32 + quad * 8) ^ xsw(t * 16 + rr)]);
                acc[t] = __builtin_amdgcn_mfma_f32_16x16x32_bf16(a, bb, acc[t], 0, 0, 0);
            }
        }
        {
            float ad = ad_sh;
            #pragma unroll
            for (int t = 0; t < 2; t++)
                #pragma unroll
                for (int r2 = 0; r2 < 4; r2++)
                    T[t][r2] = ad * T[t][r2] + acc[t][r2];
        }
        __syncthreads();    // b3: tile reads done before next-iter overwrite
    }
    float* sb = stbuf + (size_t)(bh * 4 + grp) * 4096;  // [n][p] layout
    #pragma unroll
    for (int t = 0; t < 2; t++) {
        int p = ph * 32 + t * 16 + rr;
        #pragma unroll
        for (int r2 = 0; r2 < 4; r2++)
            sb[(qb + quad * 4 + r2) * 64 + p] = T[t][r2];
    }
}

// ---------------- SSD C (p-split): y = Y_diag + Y_off + D*x for p-half ----------------
// 4 barriers/chunk; Gs aliases Bs; Xt/Shi/Slo halved (32 rows); mm1 (p-indep)
// duplicated across halves; LDS 40.2KB -> 4 blocks/CU; grid 2048.
__global__ __launch_bounds__(256) void ssd_outBC4(const ushort_t* __restrict__ xc,
        const float* __restrict__ dts, const float* __restrict__ acbuf,
        const float* __restrict__ dsk, const float* __restrict__ stbuf,
        ushort_t* __restrict__ ybuf) {
    int idx = blockIdx.x;               // 2048 = bh*8 + grp*2 + ph
    int bh = idx >> 3, grp = (idx >> 1) & 3, ph = idx & 1;
    int b = bh >> 3, h = bh & 7;
    float Dh = dsk[h];
    int tid = threadIdx.x;
    int q = tid >> 2, pb = (tid & 3) * 16;  // B/C loader (64 cols)
    int px = (tid & 3) * 8;                 // X loader (32 p-cols of half)
    int w = tid >> 6, lane = tid & 63;
    int rr = lane & 15, quad = lane >> 4, qb = w * 16;

    __shared__ ushort_t Cs[64][68], Bs[64][68], Bt[64][68],
                        Xt[32][68], Shi[32][68], Slo[32][68];
    ushort_t (&Gs)[64][68] = Bs;        // alias: Bs dead after mm1, Gs born after
    __shared__ float acum_s[64], dtq_s[64], ea_s[64], dec_s[64];
    __shared__ float ad_sh;

    // running prefix state S (p-half): row nn=qb+quad*4+r2, col p=ph*32+t*16+rr
    float S[2][4];
    #pragma unroll
    for (int t = 0; t < 2; t++)
        #pragma unroll
        for (int r2 = 0; r2 < 4; r2++) S[t][r2] = 0.f;
    for (int g = 0; g < grp; g++) {
        float Ag = 1.f;
        #pragma unroll
        for (int c = 0; c < 4; c++)
            Ag *= __expf(acbuf[((size_t)bh * 16 + g * 4 + c) * 64 + 63]);
        const float* s0 = stbuf + (size_t)(bh * 4 + g) * 4096;
        #pragma unroll
        for (int t = 0; t < 2; t++) {
            int p = ph * 32 + t * 16 + rr;
            #pragma unroll
            for (int r2 = 0; r2 < 4; r2++)
                S[t][r2] = Ag * S[t][r2] + s0[(qb + quad * 4 + r2) * 64 + p];
        }
    }

    // prefetch chunk grp*4
    ushort_t bv[16], cv[16], xv[8];
    float a_pf = 0.f, d_pf = 0.f;
    {
        int chunk = grp * 4;
        int l0 = chunk * 64;
        const ushort_t* xrow = xc + (size_t)(b * 1024 + l0 + q) * 640;
        *(short8*)&bv[0] = *(const short8*)(xrow + 512 + pb);
        *(short8*)&bv[8] = *(const short8*)(xrow + 512 + pb + 8);
        *(short8*)&cv[0] = *(const short8*)(xrow + 576 + pb);
        *(short8*)&cv[8] = *(const short8*)(xrow + 576 + pb + 8);
        *(short8*)&xv[0] = *(const short8*)(xrow + h * 64 + ph * 32 + px);
        if (tid < 64) {
            size_t cidx = (size_t)bh * 16 + chunk;
            a_pf = acbuf[cidx * 64 + tid];
            d_pf = dts[(size_t)(b * 1024 + l0 + tid) * 8 + h];
        }
    }

    int qq0 = qb + quad * 4;
    for (int c4 = 0; c4 < 4; c4++) {
        int chunk = grp * 4 + c4;
        int l0 = chunk * 64;
        // ---- P0: LDS tiles + scalars + Shi/Slo, all from regs ----
        {
            int swq = xsw(q);
            *(short8*)&Bs[q][pb ^ swq]       = *(const short8*)&bv[0];
            *(short8*)&Bs[q][(pb + 8) ^ swq] = *(const short8*)&bv[8];
            *(short8*)&Cs[q][pb ^ swq]       = *(const short8*)&cv[0];
            *(short8*)&Cs[q][(pb + 8) ^ swq] = *(const short8*)&cv[8];
        }
        #pragma unroll
        for (int j = 0; j < 8; j++) Xt[px + j][q ^ xsw(px + j)] = xv[j];
        if (tid < 64) {
            float a = a_pf;
            acum_s[tid] = a;
            ea_s[tid] = __expf(a);
            float d = d_pf;
            dtq_s[tid] = d;
            float tot = __shfl(a, 63, 64);
            dec_s[tid] = __expf(tot - a) * d;
            if (tid == 0) ad_sh = __expf(tot);
        }
        // Shi/Slo from S regs (local p rows 0..31); cvt_pk + b64 stores
        #pragma unroll
        for (int t = 0; t < 2; t++) {
            int pl = t * 16 + rr;
            uint_t h01 = cvt_pk2(S[t][0], S[t][1]);
            uint_t h23 = cvt_pk2(S[t][2], S[t][3]);
            float l0r = S[t][0] - b2f((ushort_t)h01);
            float l1r = S[t][1] - b2f((ushort_t)(h01 >> 16));
            float l2r = S[t][2] - b2f((ushort_t)h23);
            float l3r = S[t][3] - b2f((ushort_t)(h23 >> 16));
            uint_t lo01 = cvt_pk2(l0r, l1r);
            uint_t lo23 = cvt_pk2(l2r, l3r);
            int swp = xsw(pl);
            *(uint2*)&Shi[pl][qq0 ^ swp] = make_uint2(h01, h23);
            *(uint2*)&Slo[pl][qq0 ^ swp] = make_uint2(lo01, lo23);
        }
        __syncthreads();    // b1: tiles + state + scalars ready

        // ---- P1: Bt (cvt_pk), prefetch next chunk, mm1 -> packed regs ----
        {
            float dq = dec_s[q];
            #pragma unroll
            for (int j = 0; j < 16; j += 2) {
                uint_t u = cvt_pk2(b2f(bv[j]) * dq, b2f(bv[j + 1]) * dq);
                Bt[pb + j][q ^ xsw(pb + j)] = (ushort_t)u;
                Bt[pb + j + 1][q ^ xsw(pb + j + 1)] = (ushort_t)(u >> 16);
            }
        }
        if (c4 < 3) {
            int l0n = (chunk + 1) * 64;
            const ushort_t* xrow = xc + (size_t)(b * 1024 + l0n + q) * 640;
            *(short8*)&bv[0] = *(const short8*)(xrow + 512 + pb);
            *(short8*)&bv[8] = *(const short8*)(xrow + 512 + pb + 8);
            *(short8*)&cv[0] = *(const short8*)(xrow + 576 + pb);
            *(short8*)&cv[8] = *(const short8*)(xrow + 576 + pb + 8);
            *(short8*)&xv[0] = *(const short8*)(xrow + h * 64 + ph * 32 + px);
            if (tid < 64) {
                size_t cidxn = (size_t)bh * 16 + chunk + 1;
                a_pf = acbuf[cidxn * 64 + tid];
                d_pf = dts[(size_t)(b * 1024 + l0n + tid) * 8 + h];
            }
        }
        // mm1: G = C.B^T masked -> packed bf16 in regs (full 64x64, p-indep)
        uint_t gp01[4], gp23[4];
        {
            f32x4 g[4];
            #pragma unroll
            for (int t = 0; t < 4; t++) g[t] = (f32x4){0.f, 0.f, 0.f, 0.f};
            #pragma unroll
            for (int ks = 0; ks < 2; ks++) {
                short8 a = *(const short8*)(&Cs[qb + rr][(ks * 32 + quad * 8) ^ xsw(qb + rr)]);
                #pragma unroll
                for (int t = 0; t < 4; t++) {
                    short8 bb = *(const short8*)(&Bs[t * 16 + rr][(ks * 32 + quad * 8) ^ xsw(t * 16 + rr)]);
                    g[t] = __builtin_amdgcn_mfma_f32_16x16x32_bf16(a, bb, g[t], 0, 0, 0);
                }
            }
            #pragma unroll
            for (int t = 0; t < 4; t++) {
                int s = t * 16 + rr;
                float as = acum_s[s], dss = dtq_s[s];
                float vv[4];
                #pragma unroll
                for (int r2 = 0; r2 < 4; r2++) {
                    int qq = qq0 + r2;
                    vv[r2] = (s <= qq) ? g[t][r2] * __expf(acum_s[qq] - as) * dss : 0.f;
                }
                gp01[t] = cvt_pk2(vv[0], vv[1]);
                gp23[t] = cvt_pk2(vv[2], vv[3]);
            }
        }
        __syncthreads();    // b2a: all mm1 reads of Bs complete
        #pragma unroll
        for (int t = 0; t < 4; t++) {
            int s = t * 16 + rr;
            Gs[qq0][s ^ xsw(qq0)]         = (ushort_t)gp01[t];
            Gs[qq0 + 1][s ^ xsw(qq0 + 1)] = (ushort_t)(gp01[t] >> 16);
            Gs[qq0 + 2][s ^ xsw(qq0 + 2)] = (ushort_t)gp23[t];
            Gs[qq0 + 3][s ^ xsw(qq0 + 3)] = (ushort_t)(gp23[t] >> 16);
        }
        __syncthreads();    // b2b: Gs ready

        // ---- P2: mm2 (Y_diag + Y_off, p-half) + state update + y write ----
        f32x4 aD[2], aO[2];
        #pragma unroll
        for (int t = 0; t < 2; t++) { aD[t] = (f32x4){0.f,0.f,0.f,0.f}; aO[t] = (f32x4){0.f,0.f,0.f,0.f}; }
        #pragma unroll
        for (int ks = 0; ks < 2; ks++) {
            short8 ga = *(const short8*)(&Gs[qb + rr][(ks * 32 + quad * 8) ^ xsw(qb + rr)]);
            short8 ca = *(const short8*)(&Cs[qb + rr][(ks * 32 + quad * 8) ^ xsw(qb + rr)]);
            #pragma unroll
            for (int t = 0; t < 2; t++) {
                int pl = t * 16 + rr;
                int swt = xsw(pl);
                short8 xb = *(const short8*)(&Xt[pl][(ks * 32 + quad * 8) ^ swt]);
                short8 sh = *(const short8*)(&Shi[pl][(ks * 32 + quad * 8) ^ swt]);
                short8 sl = *(const short8*)(&Slo[pl][(ks * 32 + quad * 8) ^ swt]);
                aD[t] = __builtin_amdgcn_mfma_f32_16x16x32_bf16(ga, xb, aD[t], 0, 0, 0);
                aO[t] = __builtin_amdgcn_mfma_f32_16x16x32_bf16(ca, sh, aO[t], 0, 0, 0);
                aO[t] = __builtin_amdgcn_mfma_f32_16x16x32_bf16(ca, sl, aO[t], 0, 0, 0);
            }
        }
        // state update MFMA: S = ad*S + Bt^T @ X (p-half)
        {
            f32x4 acc[2];
            #pragma unroll
            for (int t = 0; t < 2; t++) acc[t] = (f32x4){0.f, 0.f, 0.f, 0.f};
            #pragma unroll
            for (int ks = 0; ks < 2; ks++) {
                short8 a = *(const short8*)(&Bt[qb + rr][(ks * 32 + quad * 8) ^ xsw(qb + rr)]);
                #pragma unroll
                for (int t = 0; t < 2; t++) {
                    short8 bb = *(const short8*)(&Xt[t * 16 + rr][(ks * 32 + quad * 8) ^ xsw(t * 16 + rr)]);
                    acc[t] = __builtin_amdgcn_mfma_f32_16x16x32_bf16(a, bb, acc[t], 0, 0, 0);
                }
            }
            #pragma unroll
            for (int t = 0; t < 2; t++) {
                int pl = t * 16 + rr;
                int p = ph * 32 + pl;
                int swp = xsw(pl);
                float yv[4];
                #pragma unroll
                for (int r2 = 0; r2 < 4; r2++) {
                    int qq = qq0 + r2;
                    yv[r2] = aD[t][r2] + ea_s[qq] * aO[t][r2] + Dh * b2f(Xt[pl][qq ^ swp]);
                }
                uint_t u01 = cvt_pk2(yv[0], yv[1]);
                uint_t u23 = cvt_pk2(yv[2], yv[3]);
                size_t base = (size_t)(b * 1024 + l0 + qq0) * 512 + h * 64 + p;
                ybuf[base]        = (ushort_t)u01;
                ybuf[base + 512]  = (ushort_t)(u01 >> 16);
                ybuf[base + 1024] = (ushort_t)u23;
                ybuf[base + 1536] = (ushort_t)(u23 >> 16);
            }
            float ad = ad_sh;
            #pragma unroll
            for (int t = 0; t < 2; t++)
                #pragma unroll
                for (int r2 = 0; r2 < 4; r2++)
                    S[t][r2] = ad * S[t][r2] + acc[t][r2];
        }
        __syncthreads();    // b3: all tile reads done before next P0 overwrite
    }
}

// ---------------- head ----------------
__global__ __launch_bounds__(256) void head_kernel(const float* __restrict__ h,
        const float* __restrict__ hw, const float* __restrict__ stdb,
        const float* __restrict__ meanb, float* __restrict__ out) {
    int blk = blockIdx.x;       // b*192 + t
    int b = blk / 192, t = blk - b * 192;
    int l = 832 + t;
    int tid = threadIdx.x;
    __shared__ float hr[256];
    hr[tid] = h[(size_t)(b * 1024 + l) * 256 + tid];
    __syncthreads();
    if (tid < 21) {
        float acc = 0.f;
        for (int k = 0; k < 256; k++) acc += hr[k] * hw[tid * 256 + k];
        out[(size_t)blk * 21 + tid] = acc * stdb[b * 21 + tid] + meanb[b * 21 + tid];
    }
}

extern "C" void kernel_launch(void* const* d_in, const int* in_sizes, int n_in,
                              void* d_out, int out_size, void* d_ws, size_t ws_size,
                              hipStream_t stream) {
    const float* x_enc  = (const float*)d_in[0];
    const float* x_mark = (const float*)d_in[1];
    const float* tokw   = (const float*)d_in[4];
    const float* tembw  = (const float*)d_in[5];
    const float* ln_g   = (const float*)d_in[6];
    const float* ln_b   = (const float*)d_in[7];
    const float* ipw    = (const float*)d_in[8];
    const float* cw     = (const float*)d_in[9];
    const float* cb     = (const float*)d_in[10];
    const float* dtb    = (const float*)d_in[11];
    const float* alog   = (const float*)d_in[12];
    const float* dsk    = (const float*)d_in[13];
    const float* gw     = (const float*)d_in[14];
    const float* opw    = (const float*)d_in[15];
    const float* hw     = (const float*)d_in[16];
    float* out = (float*)d_out;

    char* w = (char*)d_ws;
    size_t off = 0;
    auto alloc = [&](size_t bytes) -> void* {
        void* p = w + off;
        off += (bytes + 255) & ~(size_t)255;
        return p;
    };
    float* meanb  = (float*)alloc(672 * 4);
    float* stdb   = (float*)alloc(672 * 4);
    float* rstdb  = (float*)alloc(672 * 4);
    float* dts    = (float*)alloc((size_t)262144 * 4);            // 1.05 MB
    float* pebuf  = (float*)alloc((size_t)262144 * 4);            // 1.05 MB
    float* cwt    = (float*)alloc((size_t)10240 * 4);             // 40 KB
    float* hbuf   = (float*)alloc((size_t)8388608 * 4);           // 33.55 MB
    ushort_t* hbf = (ushort_t*)alloc((size_t)8388608 * 2);        // 16.78 MB
    ushort_t* zbuf= (ushort_t*)alloc((size_t)32768 * 512 * 2);    // 33.55 MB
    ushort_t* xc  = (ushort_t*)alloc((size_t)32768 * 640 * 2);    // 41.94 MB
    char* R       = (char*)alloc((size_t)71303168);               // 71.30 MB union
    ushort_t* ybuf= (ushort_t*)alloc((size_t)32768 * 512 * 2);    // 33.55 MB
    ushort_t* wipb= (ushort_t*)alloc((size_t)4 * 1280 * 256 * 2); // 2.62 MB
    ushort_t* wopb= (ushort_t*)alloc((size_t)4 * 256 * 512 * 2);  // 1.05 MB
    // region R aliases: xbuf (gemm_ip out) dies after conv+dt; stbuf/acbuf take over
    ushort_t* xbuf = (ushort_t*)R;                        // 32768 x 704 bf16 = 46.14 MB
    float* stbuf   = (float*)R;                           // 1024 x 4096 fp32 = 16.78 MB (group partials)
    float* acbuf   = (float*)(R + 67108864);              // 256*16*64 fp32 = 4.19 MB
    (void)ws_size; (void)in_sizes; (void)n_in; (void)out_size;
    // total ~236.5 MB

    stats_kernel<<<672, 256, 0, stream>>>(x_enc, meanb, stdb, rstdb);
    pe_kernel<<<1024, 256, 0, stream>>>(pebuf);
    cvt_pad_ip<<<5120, 256, 0, stream>>>(ipw, wipb);
    cvt_wop<<<2048, 256, 0, stream>>>(opw, gw, wopb);     // fold gnorm_w into Wo
    cvt_convw<<<40, 256, 0, stream>>>(cw, cwt);
    embed3_kernel<<<512, 256, 0, stream>>>(x_enc, x_mark, tokw, tembw, pebuf,
                                           meanb, rstdb, hbuf, hbf);

    for (int layer = 0; layer < 4; layer++) {
        // in_proj: 2560 blocks, XCD-affinity map, BK=64; reads hbf
        gemm_ip<<<2560, 256, 0, stream>>>(hbf, wipb + (size_t)layer * 1280 * 256,
                                          zbuf, xbuf);
        // conv (2560 blocks) + dt (128 blocks), block-uniform split
        conv_kernel<<<2688, 256, 0, stream>>>(xbuf, cwt + layer * 2560,
                                              cb + layer * 640, dtb + layer * 8,
                                              xc, dts);
        // xbuf now dead -> stbuf/acbuf overwrite region R; p-split grids 2048
        ssd_stateA4<<<2048, 256, 0, stream>>>(xc, dts, alog + layer * 8, stbuf, acbuf);
        // outBC4 computes its own group prefix from stbuf (scan folded in)
        ssd_outBC4<<<2048, 256, 0, stream>>>(xc, dts, acbuf, dsk + layer * 8,
                                             stbuf, ybuf);
        // fused gate + out_proj + residual + LN (M=32, 1024 blocks, 4/CU)
        gemm_og<<<1024, 256, 0, stream>>>(ybuf, zbuf,
                                          wopb + (size_t)layer * 256 * 512,
                                          hbuf, hbf,
                                          ln_g + layer * 256, ln_b + layer * 256);
    }

    head_kernel<<<6144, 256, 0, stream>>>(hbuf, hw, stdb, meanb, out);
}

// Round 13
// 740.463 us; speedup vs baseline: 1.1258x; 1.1258x over previous
//
#include <hip/hip_runtime.h>
#include <hip/hip_bf16.h>

// Model: 4-layer Mamba2 TS model. B=32 L=1024 DM=256 DI=512 DST=64 NH=8 HD=64
// DC=4 Q=64 chunks=16 DIP=1160(pad 1280) CONVD=640 PRED=192 CO=21.
// I/O fp32. bf16 MFMA operands, fp32 accum. WS ~236.5 MB.
// R30->R31: FINAL REVERT to R26/R29 config (best: 737.1us; rebench 746.4 ->
// noise +-5-9us). R30 p-split post-mortem: outBC4 43.4->62.1us, FETCH
// 38.9->56.1MB -- B/C tiles + mm1 duplicated across p-halves (B/C shared
// across heads -> re-reads are real HBM/L2 traffic), occupancy 16.4->18.5%
// only (barrier count/block unchanged -> serial latency didn't halve).
// Ledger (final): BK=64 GEMM plateau; pipelined dbuf bad; dt-in-wave fusion
// bad; generic XCD swizzle bad; gate-in-outBC4 bad (R23); conv-in-ip bad
// (R25); NT stores/loads bad (R27/R28); SSD p-split bad (R30).
// Good: R19 og fusion (-89us); R20 SSD prefetch (-17us); R21 ip
// XCD-affinity + scan-fold (-39us); R26 SSD bank-swizzle (-9us).

typedef unsigned short ushort_t;
typedef unsigned int uint_t;
typedef __attribute__((ext_vector_type(8))) short short8;
typedef __attribute__((ext_vector_type(4))) float f32x4;
typedef __attribute__((ext_vector_type(4))) ushort_t ushort4_t;

__device__ __forceinline__ float b2f(ushort_t u) {
    uint_t v = ((uint_t)u) << 16;
    return __builtin_bit_cast(float, v);
}
__device__ __forceinline__ ushort_t f2b(float f) {
    uint_t u = __builtin_bit_cast(uint_t, f);
    uint_t r = (u + 0x7FFFu + ((u >> 16) & 1u)) >> 16;
    return (ushort_t)r;
}
// HW packed convert: dst.lo = bf16(a), dst.hi = bf16(b), RNE (== f2b)
__device__ __forceinline__ uint_t cvt_pk2(float a, float b) {
    uint_t r;
    asm("v_cvt_pk_bf16_f32 %0, %1, %2" : "=v"(r) : "v"(a), "v"(b));
    return r;
}
__device__ __forceinline__ float silu_f(float x) {
    return x / (1.f + __expf(-x));
}
__device__ __forceinline__ void gl_lds16(const ushort_t* g, ushort_t* l) {
    __builtin_amdgcn_global_load_lds(
        (const __attribute__((address_space(1))) unsigned int*)g,
        (__attribute__((address_space(3))) unsigned int*)l, 16, 0, 0);
}
// LDS col swizzle for [64][68] tiles: breaks 16-row-step bank aliasing.
__device__ __forceinline__ int xsw(int row) {
    return (((row >> 4) ^ row) & 3) << 3;
}

// ---------------- weight converts ----------------
// in_proj w: [4][1160][256] -> bf16 [4][1280][256], rows >=1160 zero
__global__ __launch_bounds__(256) void cvt_pad_ip(const float* __restrict__ in,
        ushort_t* __restrict__ out) {
    int i = blockIdx.x * 256 + threadIdx.x;     // < 4*1280*256
    if (i >= 4 * 1280 * 256) return;
    int layer = i / (1280 * 256);
    int rem = i - layer * 1280 * 256;
    int n = rem >> 8, k = rem & 255;
    out[i] = (n < 1160) ? f2b(in[(size_t)layer * 1160 * 256 + n * 256 + k]) : (ushort_t)0;
}
// out_proj w: [4][256][512] * gw[4][512] (col of K axis) -> bf16 W' fold
__global__ __launch_bounds__(256) void cvt_wop(const float* __restrict__ in,
        const float* __restrict__ gw, ushort_t* __restrict__ out) {
    int i = blockIdx.x * 256 + threadIdx.x;     // < 524288 exactly
    int layer = i >> 17;
    int c = i & 511;
    out[i] = f2b(in[i] * gw[layer * 512 + c]);
}
// conv w: [4][640][4] -> [4][4][640] fp32 transpose
__global__ __launch_bounds__(256) void cvt_convw(const float* __restrict__ in,
        float* __restrict__ out) {
    int i = blockIdx.x * 256 + threadIdx.x;     // < 4*2560
    if (i >= 10240) return;
    int layer = i / 2560;
    int rem = i - layer * 2560;
    int k = rem / 640, ch = rem - k * 640;
    out[i] = in[layer * 2560 + ch * 4 + k];
}

// ---------------- pos-emb table: pe[l][d], computed once ----------------
__global__ __launch_bounds__(256) void pe_kernel(float* __restrict__ pe) {
    int l = blockIdx.x, d = threadIdx.x;
    float div = __expf((float)(d & ~1) * (-9.210340371976184f / 256.0f));
    float arg = (float)l * div;
    pe[l * 256 + d] = (d & 1) ? cosf(arg) : sinf(arg);
}

// ---------------- stats ----------------
__global__ __launch_bounds__(256) void stats_kernel(const float* __restrict__ xe,
        float* __restrict__ meanb, float* __restrict__ stdb, float* __restrict__ rstdb) {
    int bi = blockIdx.x;
    int b = bi / 21, c = bi - b * 21;
    int tid = threadIdx.x;
    float s = 0.f, s2 = 0.f;
    for (int l = tid; l < 1024; l += 256) {
        float v = xe[(b * 1024 + l) * 21 + c];
        s += v; s2 += v * v;
    }
    __shared__ float r1[4], r2[4];
    for (int o = 32; o > 0; o >>= 1) { s += __shfl_down(s, o, 64); s2 += __shfl_down(s2, o, 64); }
    if ((tid & 63) == 0) { r1[tid >> 6] = s; r2[tid >> 6] = s2; }
    __syncthreads();
    if (tid == 0) {
        float S = r1[0] + r1[1] + r1[2] + r1[3];
        float S2 = r2[0] + r2[1] + r2[2] + r2[3];
        float m = S * (1.f / 1024.f);
        float var = S2 * (1.f / 1024.f) - m * m;
        float sd = sqrtf(var + 1e-5f);
        meanb[bi] = m; stdb[bi] = sd; rstdb[bi] = 1.f / sd;
    }
}

// ---------------- embedding: sliding-window, tokw in registers ----------------
__global__ __launch_bounds__(256) void embed3_kernel(const float* __restrict__ xe,
        const float* __restrict__ xm, const float* __restrict__ tokw,
        const float* __restrict__ tembw, const float* __restrict__ pe,
        const float* __restrict__ meanb, const float* __restrict__ rstdb,
        float* __restrict__ h, ushort_t* __restrict__ hbf) {
    int blk = blockIdx.x;               // b*16 + tile
    int b = blk >> 4, t = blk & 15;
    int l0 = t * 64;
    int tid = threadIdx.x;              // = d
    __shared__ float xw[66][22];        // normalized x window, row0 = l0-1 (wrap)
    __shared__ float xmw[64][4];
    __shared__ float mn[21], rs[21];
    if (tid < 21) { mn[tid] = meanb[b * 21 + tid]; rs[tid] = rstdb[b * 21 + tid]; }
    float twr[63];
    {
        const float* tp = tokw + tid * 63;
        #pragma unroll
        for (int i = 0; i < 63; i++) twr[i] = tp[i];
    }
    float tbr[4];
    #pragma unroll
    for (int k = 0; k < 4; k++) tbr[k] = tembw[tid * 4 + k];
    __syncthreads();
    for (int i = tid; i < 1386; i += 256) {
        int row = i / 21, c = i - row * 21;
        int gl = (l0 - 1 + row + 1024) & 1023;
        xw[row][c] = (xe[(size_t)(b * 1024 + gl) * 21 + c] - mn[c]) * rs[c];
    }
    {
        int row = tid >> 2, c = tid & 3;
        xmw[row][c] = xm[(size_t)(b * 1024 + l0 + row) * 4 + c];
    }
    __syncthreads();
    int d = tid;
    float acc2 = 0.f, acc1 = 0.f;   // pending partial sums for out[r-2], out[r-1]
    for (int r = 0; r < 66; r++) {
        float s0 = 0.f, s1 = 0.f, s2 = 0.f;
        #pragma unroll
        for (int c = 0; c < 21; c++) {
            float xv = xw[r][c];
            s0 += xv * twr[c * 3 + 0];
            s1 += xv * twr[c * 3 + 1];
            s2 += xv * twr[c * 3 + 2];
        }
        if (r >= 2) {
            int li = r - 2;
            float acc = acc2 + s2 + pe[(size_t)(l0 + li) * 256 + d];
            #pragma unroll
            for (int k = 0; k < 4; k++) acc += xmw[li][k] * tbr[k];
            size_t o = (size_t)(b * 1024 + l0 + li) * 256 + d;
            h[o] = acc;
            hbf[o] = f2b(acc);
        }
        acc2 = acc1 + s1;
        acc1 = s0;
    }
}

// ---------------- 128x128 LDS-staged GEMM mainloop, BK=64 (2x32 panels) ----------------
template<int KDIM>
__device__ __forceinline__ void gemm128_main(const ushort_t* __restrict__ Ab,
        const ushort_t* __restrict__ Wb, ushort_t* sA, ushort_t* sW,
        f32x4 (&acc)[16], int m0, int n0) {
    int tid = threadIdx.x;
    int w = tid >> 6, lane = tid & 63;
    int wm = w >> 1, wn = w & 1;
    int rr = lane & 15, quad = lane >> 4;
    int srow0 = w * 32 + (lane >> 2);       // staging row (+ j*16)
    int skk = (lane & 3) * 8;               // staging k-offset (shorts)
    int sl0 = w * 1024 + lane * 8;          // staging LDS index (+ j*512, + p*4096)
    for (int k0 = 0; k0 < KDIM; k0 += 64) {
        __syncthreads();                    // prev MFMA reads done before overwrite
        #pragma unroll
        for (int p = 0; p < 2; p++) {
            #pragma unroll
            for (int j = 0; j < 2; j++) {
                int row = srow0 + j * 16;
                int koff = k0 + p * 32 + skk;
                gl_lds16(Ab + (size_t)(m0 + row) * KDIM + koff, &sA[p * 4096 + sl0 + j * 512]);
                gl_lds16(Wb + (size_t)(n0 + row) * KDIM + koff, &sW[p * 4096 + sl0 + j * 512]);
            }
        }
        __syncthreads();                    // compiler drains vmcnt before barrier
        #pragma unroll
        for (int p = 0; p < 2; p++) {
            short8 a[4], b[4];
            #pragma unroll
            for (int i = 0; i < 4; i++)
                a[i] = *(const short8*)&sA[p * 4096 + (wm * 64 + i * 16 + rr) * 32 + quad * 8];
            #pragma unroll
            for (int j = 0; j < 4; j++)
                b[j] = *(const short8*)&sW[p * 4096 + (wn * 64 + j * 16 + rr) * 32 + quad * 8];
            #pragma unroll
            for (int i = 0; i < 4; i++)
                #pragma unroll
                for (int j = 0; j < 4; j++)
                    acc[i * 4 + j] = __builtin_amdgcn_mfma_f32_16x16x32_bf16(a[i], b[j], acc[i * 4 + j], 0, 0, 0);
        }
    }
}

// in_proj: A[32768x256] x W[1280x256] -> split z (n<512) | xBC/dt (512<=n<1160)
// XCD-affinity map: the 10 blocks sharing an A m-tile run consecutively on one
// XCD (round-robin blk%8) -> A tile fetched from HBM once, then L2-hits.
__global__ __launch_bounds__(256) void gemm_ip(const ushort_t* __restrict__ A,
        const ushort_t* __restrict__ W, ushort_t* __restrict__ zbuf,
        ushort_t* __restrict__ xbuf) {
    int g = blockIdx.x;                 // 2560
    int xcd = g & 7, s = g >> 3;        // per-XCD sequence 0..319
    int sq = s / 10;                    // 0..31
    int tn = s - sq * 10;               // 0..9
    int tm = (sq << 3) | xcd;           // 0..255, tm%8 == xcd
    int m0 = tm * 128, n0 = tn * 128;
    __shared__ ushort_t sA[8192], sW[8192];
    f32x4 acc[16];
    #pragma unroll
    for (int i = 0; i < 16; i++) acc[i] = (f32x4){0.f, 0.f, 0.f, 0.f};
    gemm128_main<256>(A, W, sA, sW, acc, m0, n0);
    int lane = threadIdx.x & 63, w = threadIdx.x >> 6;
    int wm = w >> 1, wn = w & 1;
    int rr = lane & 15, quad = lane >> 4;
    #pragma unroll
    for (int i = 0; i < 4; i++) {
        int mrow = m0 + wm * 64 + i * 16 + quad * 4;
        #pragma unroll
        for (int j = 0; j < 4; j++) {
            int n = n0 + wn * 64 + j * 16 + rr;
            uint_t u01 = cvt_pk2(acc[i * 4 + j][0], acc[i * 4 + j][1]);
            uint_t u23 = cvt_pk2(acc[i * 4 + j][2], acc[i * 4 + j][3]);
            ushort_t vs[4] = {(ushort_t)u01, (ushort_t)(u01 >> 16),
                              (ushort_t)u23, (ushort_t)(u23 >> 16)};
            #pragma unroll
            for (int r2 = 0; r2 < 4; r2++) {
                if (n < 512) zbuf[(size_t)(mrow + r2) * 512 + n] = vs[r2];
                else if (n < 1160) xbuf[(size_t)(mrow + r2) * 704 + (n - 512)] = vs[r2];
            }
        }
    }
}

// ---------------- fused out_proj: gate(A) x W'[256x512] + residual + LN ----------------
// A = y*silu(z) bf16 (un-normalized); rms = rsqrt(mean g^2) applied POST-matmul
// (gw folded into W'). M-tile 32 -> 1024 blocks (4/CU), gate in reg-staging
// (8 elems/thread/k-step), ssq via 8-lane shfl groups; LN in epilogue.
__global__ __launch_bounds__(256) void gemm_og(const ushort_t* __restrict__ Yb,
        const ushort_t* __restrict__ Zb, const ushort_t* __restrict__ Wb,
        float* __restrict__ h, ushort_t* __restrict__ hbf,
        const float* __restrict__ lng, const float* __restrict__ lnb) {
    int m0 = blockIdx.x * 32;
    int tid = threadIdx.x;
    int w = tid >> 6, lane = tid & 63;
    int wm = w >> 1, wn = w & 1;
    int rr = lane & 15, quad = lane >> 4;
    __shared__ ushort_t sA[2048];           // [p][32][32] shorts = 4KB
    __shared__ ushort_t sW[16384];          // [p][256][32] shorts = 32KB
    __shared__ float gssq[32];
    __shared__ float rsum[32][2], rssq[32][2];

    // A gate-staging: 8 elems/thread. row = tid>>3 (0..31), kk = (tid&7)*8
    int arow = tid >> 3;
    int akk = (tid & 7) * 8;
    const ushort_t* yrow = Yb + (size_t)(m0 + arow) * 512 + akk;
    const ushort_t* zrow = Zb + (size_t)(m0 + arow) * 512 + akk;
    // ds dest: panel p = (tid&7)>>2, in-panel k = (tid&3)*8
    ushort_t* adst = &sA[((tid & 7) >> 2) * 1024 + arow * 32 + (tid & 3) * 8];

    f32x4 acc[8];
    #pragma unroll
    for (int j = 0; j < 8; j++) acc[j] = (f32x4){0.f, 0.f, 0.f, 0.f};
    float ssqr = 0.f;

    short8 y0 = *(const short8*)(yrow);
    short8 z0 = *(const short8*)(zrow);

    for (int k0 = 0; k0 < 512; k0 += 64) {
        __syncthreads();                    // prev MFMA reads done before overwrite
        // gate in registers -> ds_write A (cvt_pk pairs)
        short8 ga;
        {
            uint_t* gau = (uint_t*)&ga;
            #pragma unroll
            for (int jj = 0; jj < 8; jj += 2) {
                float g0 = b2f(((ushort_t*)&y0)[jj]) * silu_f(b2f(((ushort_t*)&z0)[jj]));
                float g1 = b2f(((ushort_t*)&y0)[jj + 1]) * silu_f(b2f(((ushort_t*)&z0)[jj + 1]));
                ssqr += g0 * g0 + g1 * g1;
                gau[jj >> 1] = cvt_pk2(g0, g1);
            }
        }
        *(short8*)adst = ga;
        // prefetch next k-step's y/z (drains with W's gl_lds at the barrier)
        if (k0 + 64 < 512) {
            y0 = *(const short8*)(yrow + k0 + 64);
            z0 = *(const short8*)(zrow + k0 + 64);
        }
        // W' staging: 256 rows x 64 k via global_load_lds
        #pragma unroll
        for (int p = 0; p < 2; p++) {
            #pragma unroll
            for (int j = 0; j < 4; j++)
                gl_lds16(Wb + (size_t)(w * 64 + j * 16 + (lane >> 2)) * 512
                             + k0 + p * 32 + (lane & 3) * 8,
                         &sW[p * 8192 + w * 2048 + j * 512 + lane * 8]);
        }
        __syncthreads();                    // drains lgkm (ds_write) + vm (gl_lds)
        #pragma unroll
        for (int p = 0; p < 2; p++) {
            short8 a = *(const short8*)&sA[p * 1024 + (wm * 16 + rr) * 32 + quad * 8];
            #pragma unroll
            for (int j = 0; j < 8; j++) {
                short8 bv = *(const short8*)&sW[p * 8192 + (wn * 128 + j * 16 + rr) * 32 + quad * 8];
                acc[j] = __builtin_amdgcn_mfma_f32_16x16x32_bf16(a, bv, acc[j], 0, 0, 0);
            }
        }
    }

    // row sum(g^2): reduce across the 8 lanes sharing a row (contiguous lanes)
    ssqr += __shfl_xor(ssqr, 1, 64);
    ssqr += __shfl_xor(ssqr, 2, 64);
    ssqr += __shfl_xor(ssqr, 4, 64);
    if ((tid & 7) == 0) gssq[arow] = ssqr;
    __syncthreads();

    float gl[8], bl[8];
    #pragma unroll
    for (int j = 0; j < 8; j++) {
        int col = wn * 128 + j * 16 + rr;
        gl[j] = lng[col]; bl[j] = lnb[col];
    }
    // pass 1: x = h + rms*acc; accumulate row stats
    #pragma unroll
    for (int r2 = 0; r2 < 4; r2++) {
        int rowl = wm * 16 + quad * 4 + r2;
        float rmsv = rsqrtf(gssq[rowl] * (1.f / 512.f) + 1e-5f);
        size_t gbase = (size_t)(m0 + rowl) * 256;
        float s = 0.f, s2 = 0.f;
        #pragma unroll
        for (int j = 0; j < 8; j++) {
            int col = wn * 128 + j * 16 + rr;
            float xv = h[gbase + col] + acc[j][r2] * rmsv;
            acc[j][r2] = xv;
            s += xv; s2 += xv * xv;
        }
        #pragma unroll
        for (int o = 1; o < 16; o <<= 1) {
            s += __shfl_xor(s, o, 64);
            s2 += __shfl_xor(s2, o, 64);
        }
        if (rr == 0) { rsum[rowl][wn] = s; rssq[rowl][wn] = s2; }
    }
    __syncthreads();
    // pass 2: LN + write h (fp32) and hbf (bf16)
    #pragma unroll
    for (int r2 = 0; r2 < 4; r2++) {
        int rowl = wm * 16 + quad * 4 + r2;
        float S = rsum[rowl][0] + rsum[rowl][1];
        float S2 = rssq[rowl][0] + rssq[rowl][1];
        float mu = S * (1.f / 256.f);
        float var = S2 * (1.f / 256.f) - mu * mu;
        float rstd = rsqrtf(var + 1e-5f);
        size_t gbase = (size_t)(m0 + rowl) * 256;
        #pragma unroll
        for (int j = 0; j < 8; j++) {
            int col = wn * 128 + j * 16 + rr;
            float o = (acc[j][r2] - mu) * rstd * gl[j] + bl[j];
            h[gbase + col] = o;
            hbf[gbase + col] = f2b(o);
        }
    }
}

// ---------------- conv (blocks < 2560) + dt (blocks >= 2560, block-uniform) ----------------
__global__ __launch_bounds__(256) void conv_kernel(const ushort_t* __restrict__ xbuf,
        const float* __restrict__ cwt, const float* __restrict__ cb,
        const float* __restrict__ dtb, ushort_t* __restrict__ xc,
        float* __restrict__ dts) {
    if (blockIdx.x >= 2560) {
        int r = (blockIdx.x - 2560) * 256 + threadIdx.x;
        short8 dv = *(const short8*)(xbuf + (size_t)r * 704 + 640);
        #pragma unroll
        for (int j = 0; j < 8; j++) {
            float x = b2f(((ushort_t*)&dv)[j]) + dtb[j];
            dts[(size_t)r * 8 + j] = (x > 20.f) ? x : log1pf(__expf(x));
        }
        return;
    }
    int idx = blockIdx.x * 256 + threadIdx.x;   // < 8192*80
    int g = idx % 80;
    int rt = idx / 80;
    int ch0 = g * 8;
    int b = rt >> 8;
    int l0 = (rt & 255) << 2;
    float wgt[4][8];
    #pragma unroll
    for (int k = 0; k < 4; k++) {
        float4 w0 = *(const float4*)(cwt + k * 640 + ch0);
        float4 w1 = *(const float4*)(cwt + k * 640 + ch0 + 4);
        wgt[k][0] = w0.x; wgt[k][1] = w0.y; wgt[k][2] = w0.z; wgt[k][3] = w0.w;
        wgt[k][4] = w1.x; wgt[k][5] = w1.y; wgt[k][6] = w1.z; wgt[k][7] = w1.w;
    }
    float bias[8];
    {
        float4 b0 = *(const float4*)(cb + ch0);
        float4 b1 = *(const float4*)(cb + ch0 + 4);
        bias[0] = b0.x; bias[1] = b0.y; bias[2] = b0.z; bias[3] = b0.w;
        bias[4] = b1.x; bias[5] = b1.y; bias[6] = b1.z; bias[7] = b1.w;
    }
    short8 xr[7];
    const ushort_t* base = xbuf + (size_t)(b * 1024 + l0) * 704 + ch0;
    #pragma unroll
    for (int i = 0; i < 7; i++) {
        int ll = l0 - 3 + i;
        if (ll >= 0) xr[i] = *(const short8*)(base + (ptrdiff_t)(i - 3) * 704);
        else         xr[i] = (short8){0, 0, 0, 0, 0, 0, 0, 0};
    }
    #pragma unroll
    for (int lo = 0; lo < 4; lo++) {
        float acc[8];
        #pragma unroll
        for (int j = 0; j < 8; j++) acc[j] = bias[j];
        #pragma unroll
        for (int k = 0; k < 4; k++) {
            #pragma unroll
            for (int j = 0; j < 8; j++)
                acc[j] += b2f(((ushort_t*)&xr[lo + k])[j]) * wgt[k][j];
        }
        short8 o;
        #pragma unroll
        for (int j = 0; j < 8; j++) ((ushort_t*)&o)[j] = f2b(silu_f(acc[j]));
        *(short8*)(xc + (size_t)(b * 1024 + l0 + lo) * 640 + ch0) = o;
    }
}

// ---------------- SSD A4: group-partial states per (b,h,grp), 4 chunks in-block ----------------
// T = ad_c*T + (B*dec)^T@X per chunk; next-chunk loads register-prefetched in P1.
// Tiles bank-swizzled via xsw(row).
__global__ __launch_bounds__(256) void ssd_stateA4(const ushort_t* __restrict__ xc,
        const float* __restrict__ dts, const float* __restrict__ alog,
        float* __restrict__ stbuf, float* __restrict__ acbuf) {
    int idx = blockIdx.x;               // 1024 = bh*4 + grp
    int bh = idx >> 2, grp = idx & 3;
    int b = bh >> 3, h = bh & 7;
    float Ah = -__expf(alog[h]);
    int tid = threadIdx.x;
    int q = tid >> 2, pb = (tid & 3) * 16;
    int w = tid >> 6, lane = tid & 63;
    int rr = lane & 15, quad = lane >> 4, qb = w * 16;

    __shared__ ushort_t Bt[64][68], Xt[64][68];
    __shared__ float dec_s[64];
    __shared__ float ad_sh;

    float T[4][4];
    #pragma unroll
    for (int t = 0; t < 4; t++)
        #pragma unroll
        for (int r2 = 0; r2 < 4; r2++) T[t][r2] = 0.f;

    // prefetch chunk grp*4
    ushort_t bv[16], xv[16];
    float d_pf = 0.f;
    {
        int chunk = grp * 4;
        int l0 = chunk * 64;
        const ushort_t* xrow = xc + (size_t)(b * 1024 + l0 + q) * 640;
        *(short8*)&bv[0] = *(const short8*)(xrow + 512 + pb);
        *(short8*)&bv[8] = *(const short8*)(xrow + 512 + pb + 8);
        *(short8*)&xv[0] = *(const short8*)(xrow + h * 64 + pb);
        *(short8*)&xv[8] = *(const short8*)(xrow + h * 64 + pb + 8);
        if (tid < 64)
            d_pf = dts[(size_t)(b * 1024 + l0 + tid) * 8 + h];
    }

    for (int c4 = 0; c4 < 4; c4++) {
        int chunk = grp * 4 + c4;
        size_t cidx = (size_t)bh * 16 + chunk;
        // P0: Xt transpose write + wave0 scalars (all from prefetched regs)
        #pragma unroll
        for (int j = 0; j < 16; j++) Xt[pb + j][q ^ xsw(pb + j)] = xv[j];
        if (tid < 64) {
            float d = d_pf;
            float a = d * Ah;
            #pragma unroll
            for (int off = 1; off < 64; off <<= 1) {
                float t = __shfl_up(a, off, 64);
                if (tid >= off) a += t;
            }
            acbuf[cidx * 64 + tid] = a;
            float tot = __shfl(a, 63, 64);
            dec_s[tid] = __expf(tot - a) * d;
            if (tid == 0) ad_sh = __expf(tot);
        }
        __syncthreads();    // b1: Xt + dec_s + ad_sh ready
        // P1: Bt from current bv (cvt_pk pairs), then prefetch next chunk
        {
            float dq = dec_s[q];
            #pragma unroll
            for (int j = 0; j < 16; j += 2) {
                uint_t u = cvt_pk2(b2f(bv[j]) * dq, b2f(bv[j + 1]) * dq);
                Bt[pb + j][q ^ xsw(pb + j)] = (ushort_t)u;
                Bt[pb + j + 1][q ^ xsw(pb + j + 1)] = (ushort_t)(u >> 16);
            }
        }
        if (c4 < 3) {
            int l0n = (chunk + 1) * 64;
            const ushort_t* xrow = xc + (size_t)(b * 1024 + l0n + q) * 640;
            *(short8*)&bv[0] = *(const short8*)(xrow + 512 + pb);
            *(short8*)&bv[8] = *(const short8*)(xrow + 512 + pb + 8);
            *(short8*)&xv[0] = *(const short8*)(xrow + h * 64 + pb);
            *(short8*)&xv[8] = *(const short8*)(xrow + h * 64 + pb + 8);
            if (tid < 64)
                d_pf = dts[(size_t)(b * 1024 + l0n + tid) * 8 + h];
        }
        __syncthreads();    // b2: Bt ready
        // P2: MFMA + T update
        f32x4 acc[4];
        #pragma unroll
        for (int t = 0; t < 4; t++) acc[t] = (f32x4){0.f, 0.f, 0.f, 0.f};
        #pragma unroll
        for (int ks = 0; ks < 2; ks++) {
            short8 a = *(const short8*)(&Bt[qb + rr][(ks * 32 + quad * 8) ^ xsw(qb + rr)]);
            #pragma unroll
            for (int t = 0; t < 4; t++) {
                short8 bb = *(const short8*)(&Xt[t * 16 + rr][(ks * 32 + quad * 8) ^ xsw(t * 16 + rr)]);
                acc[t] = __builtin_amdgcn_mfma_f32_16x16x32_bf16(a, bb, acc[t], 0, 0, 0);
            }
        }
        {
            float ad = ad_sh;
            #pragma unroll
            for (int t = 0; t < 4; t++)
                #pragma unroll
                for (int r2 = 0; r2 < 4; r2++)
                    T[t][r2] = ad * T[t][r2] + acc[t][r2];
        }
        __syncthreads();    // b3: tile reads done before next-iter overwrite
    }
    float* sb = stbuf + (size_t)idx * 4096;     // [n][p] layout
    #pragma unroll
    for (int t = 0; t < 4; t++) {
        int p = t * 16 + rr;
        #pragma unroll
        for (int r2 = 0; r2 < 4; r2++)
            sb[(qb + quad * 4 + r2) * 64 + p] = T[t][r2];
    }
}

// ---------------- SSD C: per (b,h,group-of-4): y = Y_diag + Y_off + D*x ----------------
// 4 barriers/chunk; Gs aliases Bs (LDS 53.3KB -> 3 blocks/CU); next-chunk
// loads prefetched at P1 start; group prefix from stbuf in prologue.
// Tiles bank-swizzled via xsw(row).
__global__ __launch_bounds__(256) void ssd_outBC4(const ushort_t* __restrict__ xc,
        const float* __restrict__ dts, const float* __restrict__ acbuf,
        const float* __restrict__ dsk, const float* __restrict__ stbuf,
        ushort_t* __restrict__ ybuf) {
    int idx = blockIdx.x;               // 1024 = bh*4 + grp
    int bh = idx >> 2, grp = idx & 3;
    int b = bh >> 3, h = bh & 7;
    float Dh = dsk[h];
    int tid = threadIdx.x;
    int q = tid >> 2, pb = (tid & 3) * 16;
    int w = tid >> 6, lane = tid & 63;
    int rr = lane & 15, quad = lane >> 4, qb = w * 16;

    __shared__ ushort_t Cs[64][68], Bs[64][68], Xt[64][68],
                        Bt[64][68], Shi[64][68], Slo[64][68];
    ushort_t (&Gs)[64][68] = Bs;        // alias: Bs dead after mm1, Gs born after
    __shared__ float acum_s[64], dtq_s[64], ea_s[64], dec_s[64];
    __shared__ float ad_sh;

    // running prefix state S, C/D layout: row nn=qb+quad*4+r2, col p=t*16+rr
    float S[4][4];
    #pragma unroll
    for (int t = 0; t < 4; t++)
        #pragma unroll
        for (int r2 = 0; r2 < 4; r2++) S[t][r2] = 0.f;
    for (int g = 0; g < grp; g++) {
        float Ag = 1.f;
        #pragma unroll
        for (int c = 0; c < 4; c++)
            Ag *= __expf(acbuf[((size_t)bh * 16 + g * 4 + c) * 64 + 63]);
        const float* s0 = stbuf + (size_t)(bh * 4 + g) * 4096;
        #pragma unroll
        for (int t = 0; t < 4; t++) {
            int p = t * 16 + rr;
            #pragma unroll
            for (int r2 = 0; r2 < 4; r2++)
                S[t][r2] = Ag * S[t][r2] + s0[(qb + quad * 4 + r2) * 64 + p];
        }
    }

    // prefetch chunk grp*4
    ushort_t bv[16], cv[16], xv[16];
    float a_pf = 0.f, d_pf = 0.f;
    {
        int chunk = grp * 4;
        int l0 = chunk * 64;
        const ushort_t* xrow = xc + (size_t)(b * 1024 + l0 + q) * 640;
        *(short8*)&bv[0] = *(const short8*)(xrow + 512 + pb);
        *(short8*)&bv[8] = *(const short8*)(xrow + 512 + pb + 8);
        *(short8*)&cv[0] = *(const short8*)(xrow + 576 + pb);
        *(short8*)&cv[8] = *(const short8*)(xrow + 576 + pb + 8);
        *(short8*)&xv[0] = *(const short8*)(xrow + h * 64 + pb);
        *(short8*)&xv[8] = *(const short8*)(xrow + h * 64 + pb + 8);
        if (tid < 64) {
            size_t cidx = (size_t)bh * 16 + chunk;
            a_pf = acbuf[cidx * 64 + tid];
            d_pf = dts[(size_t)(b * 1024 + l0 + tid) * 8 + h];
        }
    }

    int qq0 = qb + quad * 4;
    for (int c4 = 0; c4 < 4; c4++) {
        int chunk = grp * 4 + c4;
        int l0 = chunk * 64;
        // ---- P0: LDS tiles + scalars + Shi/Slo, all from regs ----
        {
            int swq = xsw(q);
            *(short8*)&Bs[q][pb ^ swq]       = *(const short8*)&bv[0];
            *(short8*)&Bs[q][(pb + 8) ^ swq] = *(const short8*)&bv[8];
            *(short8*)&Cs[q][pb ^ swq]       = *(const short8*)&cv[0];
            *(short8*)&Cs[q][(pb + 8) ^ swq] = *(const short8*)&cv[8];
        }
        #pragma unroll
        for (int j = 0; j < 16; j++) Xt[pb + j][q ^ xsw(pb + j)] = xv[j];
        if (tid < 64) {
            float a = a_pf;
            acum_s[tid] = a;
            ea_s[tid] = __expf(a);
            float d = d_pf;
            dtq_s[tid] = d;
            float tot = __shfl(a, 63, 64);
            dec_s[tid] = __expf(tot - a) * d;
            if (tid == 0) ad_sh = __expf(tot);
        }
        // Shi/Slo from S regs (A-operand layout [p][n]); cvt_pk + b64 stores
        #pragma unroll
        for (int t = 0; t < 4; t++) {
            int p = t * 16 + rr;
            uint_t h01 = cvt_pk2(S[t][0], S[t][1]);
            uint_t h23 = cvt_pk2(S[t][2], S[t][3]);
            float l0r = S[t][0] - b2f((ushort_t)h01);
            float l1r = S[t][1] - b2f((ushort_t)(h01 >> 16));
            float l2r = S[t][2] - b2f((ushort_t)h23);
            float l3r = S[t][3] - b2f((ushort_t)(h23 >> 16));
            uint_t lo01 = cvt_pk2(l0r, l1r);
            uint_t lo23 = cvt_pk2(l2r, l3r);
            int swp = xsw(p);
            *(uint2*)&Shi[p][qq0 ^ swp] = make_uint2(h01, h23);
            *(uint2*)&Slo[p][qq0 ^ swp] = make_uint2(lo01, lo23);
        }
        __syncthreads();    // b1: tiles + state + scalars ready

        // ---- P1: Bt (cvt_pk), prefetch next chunk, mm1 -> packed regs ----
        {
            float dq = dec_s[q];
            #pragma unroll
            for (int j = 0; j < 16; j += 2) {
                uint_t u = cvt_pk2(b2f(bv[j]) * dq, b2f(bv[j + 1]) * dq);
                Bt[pb + j][q ^ xsw(pb + j)] = (ushort_t)u;
                Bt[pb + j + 1][q ^ xsw(pb + j + 1)] = (ushort_t)(u >> 16);
            }
        }
        if (c4 < 3) {
            int l0n = (chunk + 1) * 64;
            const ushort_t* xrow = xc + (size_t)(b * 1024 + l0n + q) * 640;
            *(short8*)&bv[0] = *(const short8*)(xrow + 512 + pb);
            *(short8*)&bv[8] = *(const short8*)(xrow + 512 + pb + 8);
            *(short8*)&cv[0] = *(const short8*)(xrow + 576 + pb);
            *(short8*)&cv[8] = *(const short8*)(xrow + 576 + pb + 8);
            *(short8*)&xv[0] = *(const short8*)(xrow + h * 64 + pb);
            *(short8*)&xv[8] = *(const short8*)(xrow + h * 64 + pb + 8);
            if (tid < 64) {
                size_t cidxn = (size_t)bh * 16 + chunk + 1;
                a_pf = acbuf[cidxn * 64 + tid];
                d_pf = dts[(size_t)(b * 1024 + l0n + tid) * 8 + h];
            }
        }
        // mm1: G = C.B^T masked -> packed bf16 in regs
        uint_t gp01[4], gp23[4];
        {
            f32x4 g[4];
            #pragma unroll
            for (int t = 0; t < 4; t++) g[t] = (f32x4){0.f, 0.f, 0.f, 0.f};
            #pragma unroll
            for (int ks = 0; ks < 2; ks++) {
                short8 a = *(const short8*)(&Cs[qb + rr][(ks * 32 + quad * 8) ^ xsw(qb + rr)]);
                #pragma unroll
                for (int t = 0; t < 4; t++) {
                    short8 bb = *(const short8*)(&Bs[t * 16 + rr][(ks * 32 + quad * 8) ^ xsw(t * 16 + rr)]);
                    g[t] = __builtin_amdgcn_mfma_f32_16x16x32_bf16(a, bb, g[t], 0, 0, 0);
                }
            }
            #pragma unroll
            for (int t = 0; t < 4; t++) {
                int s = t * 16 + rr;
                float as = acum_s[s], dss = dtq_s[s];
                float vv[4];
                #pragma unroll
                for (int r2 = 0; r2 < 4; r2++) {
                    int qq = qq0 + r2;
                    vv[r2] = (s <= qq) ? g[t][r2] * __expf(acum_s[qq] - as) * dss : 0.f;
                }
                gp01[t] = cvt_pk2(vv[0], vv[1]);
                gp23[t] = cvt_pk2(vv[2], vv[3]);
            }
        }
        __syncthreads();    // b2a: all mm1 reads of Bs complete
        #pragma unroll
        for (int t = 0; t < 4; t++) {
            int s = t * 16 + rr;
            Gs[qq0][s ^ xsw(qq0)]         = (ushort_t)gp01[t];
            Gs[qq0 + 1][s ^ xsw(qq0 + 1)] = (ushort_t)(gp01[t] >> 16);
            Gs[qq0 + 2][s ^ xsw(qq0 + 2)] = (ushort_t)gp23[t];
            Gs[qq0 + 3][s ^ xsw(qq0 + 3)] = (ushort_t)(gp23[t] >> 16);
        }
        __syncthreads();    // b2b: Gs ready

        // ---- P2: mm2 (Y_diag + Y_off) + state update + y write ----
        f32x4 aD[4], aO[4];
        #pragma unroll
        for (int t = 0; t < 4; t++) { aD[t] = (f32x4){0.f,0.f,0.f,0.f}; aO[t] = (f32x4){0.f,0.f,0.f,0.f}; }
        #pragma unroll
        for (int ks = 0; ks < 2; ks++) {
            short8 ga = *(const short8*)(&Gs[qb + rr][(ks * 32 + quad * 8) ^ xsw(qb + rr)]);
            short8 ca = *(const short8*)(&Cs[qb + rr][(ks * 32 + quad * 8) ^ xsw(qb + rr)]);
            #pragma unroll
            for (int t = 0; t < 4; t++) {
                int rowt = t * 16 + rr;
                int swt = xsw(rowt);
                short8 xb = *(const short8*)(&Xt[rowt][(ks * 32 + quad * 8) ^ swt]);
                short8 sh = *(const short8*)(&Shi[rowt][(ks * 32 + quad * 8) ^ swt]);
                short8 sl = *(const short8*)(&Slo[rowt][(ks * 32 + quad * 8) ^ swt]);
                aD[t] = __builtin_amdgcn_mfma_f32_16x16x32_bf16(ga, xb, aD[t], 0, 0, 0);
                aO[t] = __builtin_amdgcn_mfma_f32_16x16x32_bf16(ca, sh, aO[t], 0, 0, 0);
                aO[t] = __builtin_amdgcn_mfma_f32_16x16x32_bf16(ca, sl, aO[t], 0, 0, 0);
            }
        }
        // state update MFMA: S = ad*S + Bt^T @ X
        {
            f32x4 acc[4];
            #pragma unroll
            for (int t = 0; t < 4; t++) acc[t] = (f32x4){0.f, 0.f, 0.f, 0.f};
            #pragma unroll
            for (int ks = 0; ks < 2; ks++) {
                short8 a = *(const short8*)(&Bt[qb + rr][(ks * 32 + quad * 8) ^ xsw(qb + rr)]);
                #pragma unroll
                for (int t = 0; t < 4; t++) {
                    short8 bb = *(const short8*)(&Xt[t * 16 + rr][(ks * 32 + quad * 8) ^ xsw(t * 16 + rr)]);
                    acc[t] = __builtin_amdgcn_mfma_f32_16x16x32_bf16(a, bb, acc[t], 0, 0, 0);
                }
            }
            #pragma unroll
            for (int t = 0; t < 4; t++) {
                int p = t * 16 + rr;
                int swp = xsw(p);
                float yv[4];
                #pragma unroll
                for (int r2 = 0; r2 < 4; r2++) {
                    int qq = qq0 + r2;
                    yv[r2] = aD[t][r2] + ea_s[qq] * aO[t][r2] + Dh * b2f(Xt[p][qq ^ swp]);
                }
                uint_t u01 = cvt_pk2(yv[0], yv[1]);
                uint_t u23 = cvt_pk2(yv[2], yv[3]);
                size_t base = (size_t)(b * 1024 + l0 + qq0) * 512 + h * 64 + p;
                ybuf[base]        = (ushort_t)u01;
                ybuf[base + 512]  = (ushort_t)(u01 >> 16);
                ybuf[base + 1024] = (ushort_t)u23;
                ybuf[base + 1536] = (ushort_t)(u23 >> 16);
            }
            float ad = ad_sh;
            #pragma unroll
            for (int t = 0; t < 4; t++)
                #pragma unroll
                for (int r2 = 0; r2 < 4; r2++)
                    S[t][r2] = ad * S[t][r2] + acc[t][r2];
        }
        __syncthreads();    // b3: all tile reads done before next P0 overwrite
    }
}

// ---------------- head ----------------
__global__ __launch_bounds__(256) void head_kernel(const float* __restrict__ h,
        const float* __restrict__ hw, const float* __restrict__ stdb,
        const float* __restrict__ meanb, float* __restrict__ out) {
    int blk = blockIdx.x;       // b*192 + t
    int b = blk / 192, t = blk - b * 192;
    int l = 832 + t;
    int tid = threadIdx.x;
    __shared__ float hr[256];
    hr[tid] = h[(size_t)(b * 1024 + l) * 256 + tid];
    __syncthreads();
    if (tid < 21) {
        float acc = 0.f;
        for (int k = 0; k < 256; k++) acc += hr[k] * hw[tid * 256 + k];
        out[(size_t)blk * 21 + tid] = acc * stdb[b * 21 + tid] + meanb[b * 21 + tid];
    }
}

extern "C" void kernel_launch(void* const* d_in, const int* in_sizes, int n_in,
                              void* d_out, int out_size, void* d_ws, size_t ws_size,
                              hipStream_t stream) {
    const float* x_enc  = (const float*)d_in[0];
    const float* x_mark = (const float*)d_in[1];
    const float* tokw   = (const float*)d_in[4];
    const float* tembw  = (const float*)d_in[5];
    const float* ln_g   = (const float*)d_in[6];
    const float* ln_b   = (const float*)d_in[7];
    const float* ipw    = (const float*)d_in[8];
    const float* cw     = (const float*)d_in[9];
    const float* cb     = (const float*)d_in[10];
    const float* dtb    = (const float*)d_in[11];
    const float* alog   = (const float*)d_in[12];
    const float* dsk    = (const float*)d_in[13];
    const float* gw     = (const float*)d_in[14];
    const float* opw    = (const float*)d_in[15];
    const float* hw     = (const float*)d_in[16];
    float* out = (float*)d_out;

    char* w = (char*)d_ws;
    size_t off = 0;
    auto alloc = [&](size_t bytes) -> void* {
        void* p = w + off;
        off += (bytes + 255) & ~(size_t)255;
        return p;
    };
    float* meanb  = (float*)alloc(672 * 4);
    float* stdb   = (float*)alloc(672 * 4);
    float* rstdb  = (float*)alloc(672 * 4);
    float* dts    = (float*)alloc((size_t)262144 * 4);            // 1.05 MB
    float* pebuf  = (float*)alloc((size_t)262144 * 4);            // 1.05 MB
    float* cwt    = (float*)alloc((size_t)10240 * 4);             // 40 KB
    float* hbuf   = (float*)alloc((size_t)8388608 * 4);           // 33.55 MB
    ushort_t* hbf = (ushort_t*)alloc((size_t)8388608 * 2);        // 16.78 MB
    ushort_t* zbuf= (ushort_t*)alloc((size_t)32768 * 512 * 2);    // 33.55 MB
    ushort_t* xc  = (ushort_t*)alloc((size_t)32768 * 640 * 2);    // 41.94 MB
    char* R       = (char*)alloc((size_t)71303168);               // 71.30 MB union
    ushort_t* ybuf= (ushort_t*)alloc((size_t)32768 * 512 * 2);    // 33.55 MB
    ushort_t* wipb= (ushort_t*)alloc((size_t)4 * 1280 * 256 * 2); // 2.62 MB
    ushort_t* wopb= (ushort_t*)alloc((size_t)4 * 256 * 512 * 2);  // 1.05 MB
    // region R aliases: xbuf (gemm_ip out) dies after conv+dt; stbuf/acbuf take over
    ushort_t* xbuf = (ushort_t*)R;                        // 32768 x 704 bf16 = 46.14 MB
    float* stbuf   = (float*)R;                           // 1024 x 4096 fp32 = 16.78 MB (group partials)
    float* acbuf   = (float*)(R + 67108864);              // 256*16*64 fp32 = 4.19 MB
    (void)ws_size; (void)in_sizes; (void)n_in; (void)out_size;
    // total ~236.5 MB

    stats_kernel<<<672, 256, 0, stream>>>(x_enc, meanb, stdb, rstdb);
    pe_kernel<<<1024, 256, 0, stream>>>(pebuf);
    cvt_pad_ip<<<5120, 256, 0, stream>>>(ipw, wipb);
    cvt_wop<<<2048, 256, 0, stream>>>(opw, gw, wopb);     // fold gnorm_w into Wo
    cvt_convw<<<40, 256, 0, stream>>>(cw, cwt);
    embed3_kernel<<<512, 256, 0, stream>>>(x_enc, x_mark, tokw, tembw, pebuf,
                                           meanb, rstdb, hbuf, hbf);

    for (int layer = 0; layer < 4; layer++) {
        // in_proj: 2560 blocks, XCD-affinity map, BK=64; reads hbf
        gemm_ip<<<2560, 256, 0, stream>>>(hbf, wipb + (size_t)layer * 1280 * 256,
                                          zbuf, xbuf);
        // conv (2560 blocks) + dt (128 blocks), block-uniform split
        conv_kernel<<<2688, 256, 0, stream>>>(xbuf, cwt + layer * 2560,
                                              cb + layer * 640, dtb + layer * 8,
                                              xc, dts);
        // xbuf now dead -> stbuf/acbuf overwrite region R
        ssd_stateA4<<<1024, 256, 0, stream>>>(xc, dts, alog + layer * 8, stbuf, acbuf);
        // outBC4 computes its own group prefix from stbuf (scan folded in)
        ssd_outBC4<<<1024, 256, 0, stream>>>(xc, dts, acbuf, dsk + layer * 8,
                                             stbuf, ybuf);
        // fused gate + out_proj + residual + LN (M=32, 1024 blocks, 4/CU)
        gemm_og<<<1024, 256, 0, stream>>>(ybuf, zbuf,
                                          wopb + (size_t)layer * 256 * 512,
                                          hbuf, hbf,
                                          ln_g + layer * 256, ln_b + layer * 256);
    }

    head_kernel<<<6144, 256, 0, stream>>>(hbuf, hw, stdb, meanb, out);
}

// Round 14
// 733.829 us; speedup vs baseline: 1.1360x; 1.0090x over previous
//
#include <hip/hip_runtime.h>
#include <hip/hip_bf16.h>

// Model: 4-layer Mamba2 TS model. B=32 L=1024 DM=256 DI=512 DST=64 NH=8 HD=64
// DC=4 Q=64 chunks=16 DIP=1160(pad 1280) CONVD=640 PRED=192 CO=21.
// I/O fp32. bf16 MFMA operands, fp32 accum. WS ~236.5 MB.
// R31->R32: SSD XCD-affinity remap (R21 mechanism applied to SSD pair):
// blocks sharing batch b (8 heads x 4 grps = 32 blocks, all reading the SAME
// xc[b] B/C panels + stbuf[bh] rows) now co-locate on one XCD via b = xcd
// (mod 8): per-XCD xc footprint 4x1.31MB ~ L2. Bijective index permutation
// only -- zero numerics change. (R30's p-split failed by DUPLICATING loads;
// this shares them. Generic swizzle failed by SPREADING sharers; this
// co-locates them.)
// Ledger: BK=64 GEMM plateau; pipelined dbuf bad; dt-in-wave fusion bad;
// generic XCD swizzle bad; gate-in-outBC4 bad (R23); conv-in-ip bad (R25);
// NT stores/loads bad (R27/R28); SSD p-split bad (R30).
// Good: R19 og fusion (-89us); R20 SSD prefetch (-17us); R21 ip
// XCD-affinity + scan-fold (-39us); R26 SSD bank-swizzle (-9us).
// Baseline R26/R29/R31: 737-746us.

typedef unsigned short ushort_t;
typedef unsigned int uint_t;
typedef __attribute__((ext_vector_type(8))) short short8;
typedef __attribute__((ext_vector_type(4))) float f32x4;
typedef __attribute__((ext_vector_type(4))) ushort_t ushort4_t;

__device__ __forceinline__ float b2f(ushort_t u) {
    uint_t v = ((uint_t)u) << 16;
    return __builtin_bit_cast(float, v);
}
__device__ __forceinline__ ushort_t f2b(float f) {
    uint_t u = __builtin_bit_cast(uint_t, f);
    uint_t r = (u + 0x7FFFu + ((u >> 16) & 1u)) >> 16;
    return (ushort_t)r;
}
// HW packed convert: dst.lo = bf16(a), dst.hi = bf16(b), RNE (== f2b)
__device__ __forceinline__ uint_t cvt_pk2(float a, float b) {
    uint_t r;
    asm("v_cvt_pk_bf16_f32 %0, %1, %2" : "=v"(r) : "v"(a), "v"(b));
    return r;
}
__device__ __forceinline__ float silu_f(float x) {
    return x / (1.f + __expf(-x));
}
__device__ __forceinline__ void gl_lds16(const ushort_t* g, ushort_t* l) {
    __builtin_amdgcn_global_load_lds(
        (const __attribute__((address_space(1))) unsigned int*)g,
        (__attribute__((address_space(3))) unsigned int*)l, 16, 0, 0);
}
// LDS col swizzle for [64][68] tiles: breaks 16-row-step bank aliasing.
__device__ __forceinline__ int xsw(int row) {
    return (((row >> 4) ^ row) & 3) << 3;
}

// ---------------- weight converts ----------------
// in_proj w: [4][1160][256] -> bf16 [4][1280][256], rows >=1160 zero
__global__ __launch_bounds__(256) void cvt_pad_ip(const float* __restrict__ in,
        ushort_t* __restrict__ out) {
    int i = blockIdx.x * 256 + threadIdx.x;     // < 4*1280*256
    if (i >= 4 * 1280 * 256) return;
    int layer = i / (1280 * 256);
    int rem = i - layer * 1280 * 256;
    int n = rem >> 8, k = rem & 255;
    out[i] = (n < 1160) ? f2b(in[(size_t)layer * 1160 * 256 + n * 256 + k]) : (ushort_t)0;
}
// out_proj w: [4][256][512] * gw[4][512] (col of K axis) -> bf16 W' fold
__global__ __launch_bounds__(256) void cvt_wop(const float* __restrict__ in,
        const float* __restrict__ gw, ushort_t* __restrict__ out) {
    int i = blockIdx.x * 256 + threadIdx.x;     // < 524288 exactly
    int layer = i >> 17;
    int c = i & 511;
    out[i] = f2b(in[i] * gw[layer * 512 + c]);
}
// conv w: [4][640][4] -> [4][4][640] fp32 transpose
__global__ __launch_bounds__(256) void cvt_convw(const float* __restrict__ in,
        float* __restrict__ out) {
    int i = blockIdx.x * 256 + threadIdx.x;     // < 4*2560
    if (i >= 10240) return;
    int layer = i / 2560;
    int rem = i - layer * 2560;
    int k = rem / 640, ch = rem - k * 640;
    out[i] = in[layer * 2560 + ch * 4 + k];
}

// ---------------- pos-emb table: pe[l][d], computed once ----------------
__global__ __launch_bounds__(256) void pe_kernel(float* __restrict__ pe) {
    int l = blockIdx.x, d = threadIdx.x;
    float div = __expf((float)(d & ~1) * (-9.210340371976184f / 256.0f));
    float arg = (float)l * div;
    pe[l * 256 + d] = (d & 1) ? cosf(arg) : sinf(arg);
}

// ---------------- stats ----------------
__global__ __launch_bounds__(256) void stats_kernel(const float* __restrict__ xe,
        float* __restrict__ meanb, float* __restrict__ stdb, float* __restrict__ rstdb) {
    int bi = blockIdx.x;
    int b = bi / 21, c = bi - b * 21;
    int tid = threadIdx.x;
    float s = 0.f, s2 = 0.f;
    for (int l = tid; l < 1024; l += 256) {
        float v = xe[(b * 1024 + l) * 21 + c];
        s += v; s2 += v * v;
    }
    __shared__ float r1[4], r2[4];
    for (int o = 32; o > 0; o >>= 1) { s += __shfl_down(s, o, 64); s2 += __shfl_down(s2, o, 64); }
    if ((tid & 63) == 0) { r1[tid >> 6] = s; r2[tid >> 6] = s2; }
    __syncthreads();
    if (tid == 0) {
        float S = r1[0] + r1[1] + r1[2] + r1[3];
        float S2 = r2[0] + r2[1] + r2[2] + r2[3];
        float m = S * (1.f / 1024.f);
        float var = S2 * (1.f / 1024.f) - m * m;
        float sd = sqrtf(var + 1e-5f);
        meanb[bi] = m; stdb[bi] = sd; rstdb[bi] = 1.f / sd;
    }
}

// ---------------- embedding: sliding-window, tokw in registers ----------------
__global__ __launch_bounds__(256) void embed3_kernel(const float* __restrict__ xe,
        const float* __restrict__ xm, const float* __restrict__ tokw,
        const float* __restrict__ tembw, const float* __restrict__ pe,
        const float* __restrict__ meanb, const float* __restrict__ rstdb,
        float* __restrict__ h, ushort_t* __restrict__ hbf) {
    int blk = blockIdx.x;               // b*16 + tile
    int b = blk >> 4, t = blk & 15;
    int l0 = t * 64;
    int tid = threadIdx.x;              // = d
    __shared__ float xw[66][22];        // normalized x window, row0 = l0-1 (wrap)
    __shared__ float xmw[64][4];
    __shared__ float mn[21], rs[21];
    if (tid < 21) { mn[tid] = meanb[b * 21 + tid]; rs[tid] = rstdb[b * 21 + tid]; }
    float twr[63];
    {
        const float* tp = tokw + tid * 63;
        #pragma unroll
        for (int i = 0; i < 63; i++) twr[i] = tp[i];
    }
    float tbr[4];
    #pragma unroll
    for (int k = 0; k < 4; k++) tbr[k] = tembw[tid * 4 + k];
    __syncthreads();
    for (int i = tid; i < 1386; i += 256) {
        int row = i / 21, c = i - row * 21;
        int gl = (l0 - 1 + row + 1024) & 1023;
        xw[row][c] = (xe[(size_t)(b * 1024 + gl) * 21 + c] - mn[c]) * rs[c];
    }
    {
        int row = tid >> 2, c = tid & 3;
        xmw[row][c] = xm[(size_t)(b * 1024 + l0 + row) * 4 + c];
    }
    __syncthreads();
    int d = tid;
    float acc2 = 0.f, acc1 = 0.f;   // pending partial sums for out[r-2], out[r-1]
    for (int r = 0; r < 66; r++) {
        float s0 = 0.f, s1 = 0.f, s2 = 0.f;
        #pragma unroll
        for (int c = 0; c < 21; c++) {
            float xv = xw[r][c];
            s0 += xv * twr[c * 3 + 0];
            s1 += xv * twr[c * 3 + 1];
            s2 += xv * twr[c * 3 + 2];
        }
        if (r >= 2) {
            int li = r - 2;
            float acc = acc2 + s2 + pe[(size_t)(l0 + li) * 256 + d];
            #pragma unroll
            for (int k = 0; k < 4; k++) acc += xmw[li][k] * tbr[k];
            size_t o = (size_t)(b * 1024 + l0 + li) * 256 + d;
            h[o] = acc;
            hbf[o] = f2b(acc);
        }
        acc2 = acc1 + s1;
        acc1 = s0;
    }
}

// ---------------- 128x128 LDS-staged GEMM mainloop, BK=64 (2x32 panels) ----------------
template<int KDIM>
__device__ __forceinline__ void gemm128_main(const ushort_t* __restrict__ Ab,
        const ushort_t* __restrict__ Wb, ushort_t* sA, ushort_t* sW,
        f32x4 (&acc)[16], int m0, int n0) {
    int tid = threadIdx.x;
    int w = tid >> 6, lane = tid & 63;
    int wm = w >> 1, wn = w & 1;
    int rr = lane & 15, quad = lane >> 4;
    int srow0 = w * 32 + (lane >> 2);       // staging row (+ j*16)
    int skk = (lane & 3) * 8;               // staging k-offset (shorts)
    int sl0 = w * 1024 + lane * 8;          // staging LDS index (+ j*512, + p*4096)
    for (int k0 = 0; k0 < KDIM; k0 += 64) {
        __syncthreads();                    // prev MFMA reads done before overwrite
        #pragma unroll
        for (int p = 0; p < 2; p++) {
            #pragma unroll
            for (int j = 0; j < 2; j++) {
                int row = srow0 + j * 16;
                int koff = k0 + p * 32 + skk;
                gl_lds16(Ab + (size_t)(m0 + row) * KDIM + koff, &sA[p * 4096 + sl0 + j * 512]);
                gl_lds16(Wb + (size_t)(n0 + row) * KDIM + koff, &sW[p * 4096 + sl0 + j * 512]);
            }
        }
        __syncthreads();                    // compiler drains vmcnt before barrier
        #pragma unroll
        for (int p = 0; p < 2; p++) {
            short8 a[4], b[4];
            #pragma unroll
            for (int i = 0; i < 4; i++)
                a[i] = *(const short8*)&sA[p * 4096 + (wm * 64 + i * 16 + rr) * 32 + quad * 8];
            #pragma unroll
            for (int j = 0; j < 4; j++)
                b[j] = *(const short8*)&sW[p * 4096 + (wn * 64 + j * 16 + rr) * 32 + quad * 8];
            #pragma unroll
            for (int i = 0; i < 4; i++)
                #pragma unroll
                for (int j = 0; j < 4; j++)
                    acc[i * 4 + j] = __builtin_amdgcn_mfma_f32_16x16x32_bf16(a[i], b[j], acc[i * 4 + j], 0, 0, 0);
        }
    }
}

// in_proj: A[32768x256] x W[1280x256] -> split z (n<512) | xBC/dt (512<=n<1160)
// XCD-affinity map: the 10 blocks sharing an A m-tile run consecutively on one
// XCD (round-robin blk%8) -> A tile fetched from HBM once, then L2-hits.
__global__ __launch_bounds__(256) void gemm_ip(const ushort_t* __restrict__ A,
        const ushort_t* __restrict__ W, ushort_t* __restrict__ zbuf,
        ushort_t* __restrict__ xbuf) {
    int g = blockIdx.x;                 // 2560
    int xcd = g & 7, s = g >> 3;        // per-XCD sequence 0..319
    int sq = s / 10;                    // 0..31
    int tn = s - sq * 10;               // 0..9
    int tm = (sq << 3) | xcd;           // 0..255, tm%8 == xcd
    int m0 = tm * 128, n0 = tn * 128;
    __shared__ ushort_t sA[8192], sW[8192];
    f32x4 acc[16];
    #pragma unroll
    for (int i = 0; i < 16; i++) acc[i] = (f32x4){0.f, 0.f, 0.f, 0.f};
    gemm128_main<256>(A, W, sA, sW, acc, m0, n0);
    int lane = threadIdx.x & 63, w = threadIdx.x >> 6;
    int wm = w >> 1, wn = w & 1;
    int rr = lane & 15, quad = lane >> 4;
    #pragma unroll
    for (int i = 0; i < 4; i++) {
        int mrow = m0 + wm * 64 + i * 16 + quad * 4;
        #pragma unroll
        for (int j = 0; j < 4; j++) {
            int n = n0 + wn * 64 + j * 16 + rr;
            uint_t u01 = cvt_pk2(acc[i * 4 + j][0], acc[i * 4 + j][1]);
            uint_t u23 = cvt_pk2(acc[i * 4 + j][2], acc[i * 4 + j][3]);
            ushort_t vs[4] = {(ushort_t)u01, (ushort_t)(u01 >> 16),
                              (ushort_t)u23, (ushort_t)(u23 >> 16)};
            #pragma unroll
            for (int r2 = 0; r2 < 4; r2++) {
                if (n < 512) zbuf[(size_t)(mrow + r2) * 512 + n] = vs[r2];
                else if (n < 1160) xbuf[(size_t)(mrow + r2) * 704 + (n - 512)] = vs[r2];
            }
        }
    }
}

// ---------------- fused out_proj: gate(A) x W'[256x512] + residual + LN ----------------
// A = y*silu(z) bf16 (un-normalized); rms = rsqrt(mean g^2) applied POST-matmul
// (gw folded into W'). M-tile 32 -> 1024 blocks (4/CU), gate in reg-staging
// (8 elems/thread/k-step), ssq via 8-lane shfl groups; LN in epilogue.
__global__ __launch_bounds__(256) void gemm_og(const ushort_t* __restrict__ Yb,
        const ushort_t* __restrict__ Zb, const ushort_t* __restrict__ Wb,
        float* __restrict__ h, ushort_t* __restrict__ hbf,
        const float* __restrict__ lng, const float* __restrict__ lnb) {
    int m0 = blockIdx.x * 32;
    int tid = threadIdx.x;
    int w = tid >> 6, lane = tid & 63;
    int wm = w >> 1, wn = w & 1;
    int rr = lane & 15, quad = lane >> 4;
    __shared__ ushort_t sA[2048];           // [p][32][32] shorts = 4KB
    __shared__ ushort_t sW[16384];          // [p][256][32] shorts = 32KB
    __shared__ float gssq[32];
    __shared__ float rsum[32][2], rssq[32][2];

    // A gate-staging: 8 elems/thread. row = tid>>3 (0..31), kk = (tid&7)*8
    int arow = tid >> 3;
    int akk = (tid & 7) * 8;
    const ushort_t* yrow = Yb + (size_t)(m0 + arow) * 512 + akk;
    const ushort_t* zrow = Zb + (size_t)(m0 + arow) * 512 + akk;
    // ds dest: panel p = (tid&7)>>2, in-panel k = (tid&3)*8
    ushort_t* adst = &sA[((tid & 7) >> 2) * 1024 + arow * 32 + (tid & 3) * 8];

    f32x4 acc[8];
    #pragma unroll
    for (int j = 0; j < 8; j++) acc[j] = (f32x4){0.f, 0.f, 0.f, 0.f};
    float ssqr = 0.f;

    short8 y0 = *(const short8*)(yrow);
    short8 z0 = *(const short8*)(zrow);

    for (int k0 = 0; k0 < 512; k0 += 64) {
        __syncthreads();                    // prev MFMA reads done before overwrite
        // gate in registers -> ds_write A (cvt_pk pairs)
        short8 ga;
        {
            uint_t* gau = (uint_t*)&ga;
            #pragma unroll
            for (int jj = 0; jj < 8; jj += 2) {
                float g0 = b2f(((ushort_t*)&y0)[jj]) * silu_f(b2f(((ushort_t*)&z0)[jj]));
                float g1 = b2f(((ushort_t*)&y0)[jj + 1]) * silu_f(b2f(((ushort_t*)&z0)[jj + 1]));
                ssqr += g0 * g0 + g1 * g1;
                gau[jj >> 1] = cvt_pk2(g0, g1);
            }
        }
        *(short8*)adst = ga;
        // prefetch next k-step's y/z (drains with W's gl_lds at the barrier)
        if (k0 + 64 < 512) {
            y0 = *(const short8*)(yrow + k0 + 64);
            z0 = *(const short8*)(zrow + k0 + 64);
        }
        // W' staging: 256 rows x 64 k via global_load_lds
        #pragma unroll
        for (int p = 0; p < 2; p++) {
            #pragma unroll
            for (int j = 0; j < 4; j++)
                gl_lds16(Wb + (size_t)(w * 64 + j * 16 + (lane >> 2)) * 512
                             + k0 + p * 32 + (lane & 3) * 8,
                         &sW[p * 8192 + w * 2048 + j * 512 + lane * 8]);
        }
        __syncthreads();                    // drains lgkm (ds_write) + vm (gl_lds)
        #pragma unroll
        for (int p = 0; p < 2; p++) {
            short8 a = *(const short8*)&sA[p * 1024 + (wm * 16 + rr) * 32 + quad * 8];
            #pragma unroll
            for (int j = 0; j < 8; j++) {
                short8 bv = *(const short8*)&sW[p * 8192 + (wn * 128 + j * 16 + rr) * 32 + quad * 8];
                acc[j] = __builtin_amdgcn_mfma_f32_16x16x32_bf16(a, bv, acc[j], 0, 0, 0);
            }
        }
    }

    // row sum(g^2): reduce across the 8 lanes sharing a row (contiguous lanes)
    ssqr += __shfl_xor(ssqr, 1, 64);
    ssqr += __shfl_xor(ssqr, 2, 64);
    ssqr += __shfl_xor(ssqr, 4, 64);
    if ((tid & 7) == 0) gssq[arow] = ssqr;
    __syncthreads();

    float gl[8], bl[8];
    #pragma unroll
    for (int j = 0; j < 8; j++) {
        int col = wn * 128 + j * 16 + rr;
        gl[j] = lng[col]; bl[j] = lnb[col];
    }
    // pass 1: x = h + rms*acc; accumulate row stats
    #pragma unroll
    for (int r2 = 0; r2 < 4; r2++) {
        int rowl = wm * 16 + quad * 4 + r2;
        float rmsv = rsqrtf(gssq[rowl] * (1.f / 512.f) + 1e-5f);
        size_t gbase = (size_t)(m0 + rowl) * 256;
        float s = 0.f, s2 = 0.f;
        #pragma unroll
        for (int j = 0; j < 8; j++) {
            int col = wn * 128 + j * 16 + rr;
            float xv = h[gbase + col] + acc[j][r2] * rmsv;
            acc[j][r2] = xv;
            s += xv; s2 += xv * xv;
        }
        #pragma unroll
        for (int o = 1; o < 16; o <<= 1) {
            s += __shfl_xor(s, o, 64);
            s2 += __shfl_xor(s2, o, 64);
        }
        if (rr == 0) { rsum[rowl][wn] = s; rssq[rowl][wn] = s2; }
    }
    __syncthreads();
    // pass 2: LN + write h (fp32) and hbf (bf16)
    #pragma unroll
    for (int r2 = 0; r2 < 4; r2++) {
        int rowl = wm * 16 + quad * 4 + r2;
        float S = rsum[rowl][0] + rsum[rowl][1];
        float S2 = rssq[rowl][0] + rssq[rowl][1];
        float mu = S * (1.f / 256.f);
        float var = S2 * (1.f / 256.f) - mu * mu;
        float rstd = rsqrtf(var + 1e-5f);
        size_t gbase = (size_t)(m0 + rowl) * 256;
        #pragma unroll
        for (int j = 0; j < 8; j++) {
            int col = wn * 128 + j * 16 + rr;
            float o = (acc[j][r2] - mu) * rstd * gl[j] + bl[j];
            h[gbase + col] = o;
            hbf[gbase + col] = f2b(o);
        }
    }
}

// ---------------- conv (blocks < 2560) + dt (blocks >= 2560, block-uniform) ----------------
__global__ __launch_bounds__(256) void conv_kernel(const ushort_t* __restrict__ xbuf,
        const float* __restrict__ cwt, const float* __restrict__ cb,
        const float* __restrict__ dtb, ushort_t* __restrict__ xc,
        float* __restrict__ dts) {
    if (blockIdx.x >= 2560) {
        int r = (blockIdx.x - 2560) * 256 + threadIdx.x;
        short8 dv = *(const short8*)(xbuf + (size_t)r * 704 + 640);
        #pragma unroll
        for (int j = 0; j < 8; j++) {
            float x = b2f(((ushort_t*)&dv)[j]) + dtb[j];
            dts[(size_t)r * 8 + j] = (x > 20.f) ? x : log1pf(__expf(x));
        }
        return;
    }
    int idx = blockIdx.x * 256 + threadIdx.x;   // < 8192*80
    int g = idx % 80;
    int rt = idx / 80;
    int ch0 = g * 8;
    int b = rt >> 8;
    int l0 = (rt & 255) << 2;
    float wgt[4][8];
    #pragma unroll
    for (int k = 0; k < 4; k++) {
        float4 w0 = *(const float4*)(cwt + k * 640 + ch0);
        float4 w1 = *(const float4*)(cwt + k * 640 + ch0 + 4);
        wgt[k][0] = w0.x; wgt[k][1] = w0.y; wgt[k][2] = w0.z; wgt[k][3] = w0.w;
        wgt[k][4] = w1.x; wgt[k][5] = w1.y; wgt[k][6] = w1.z; wgt[k][7] = w1.w;
    }
    float bias[8];
    {
        float4 b0 = *(const float4*)(cb + ch0);
        float4 b1 = *(const float4*)(cb + ch0 + 4);
        bias[0] = b0.x; bias[1] = b0.y; bias[2] = b0.z; bias[3] = b0.w;
        bias[4] = b1.x; bias[5] = b1.y; bias[6] = b1.z; bias[7] = b1.w;
    }
    short8 xr[7];
    const ushort_t* base = xbuf + (size_t)(b * 1024 + l0) * 704 + ch0;
    #pragma unroll
    for (int i = 0; i < 7; i++) {
        int ll = l0 - 3 + i;
        if (ll >= 0) xr[i] = *(const short8*)(base + (ptrdiff_t)(i - 3) * 704);
        else         xr[i] = (short8){0, 0, 0, 0, 0, 0, 0, 0};
    }
    #pragma unroll
    for (int lo = 0; lo < 4; lo++) {
        float acc[8];
        #pragma unroll
        for (int j = 0; j < 8; j++) acc[j] = bias[j];
        #pragma unroll
        for (int k = 0; k < 4; k++) {
            #pragma unroll
            for (int j = 0; j < 8; j++)
                acc[j] += b2f(((ushort_t*)&xr[lo + k])[j]) * wgt[k][j];
        }
        short8 o;
        #pragma unroll
        for (int j = 0; j < 8; j++) ((ushort_t*)&o)[j] = f2b(silu_f(acc[j]));
        *(short8*)(xc + (size_t)(b * 1024 + l0 + lo) * 640 + ch0) = o;
    }
}

// ---------------- SSD A4: group-partial states per (b,h,grp), 4 chunks in-block ----------------
// T = ad_c*T + (B*dec)^T@X per chunk; next-chunk loads register-prefetched in P1.
// Tiles bank-swizzled via xsw(row). XCD-affinity: blocks of batch b co-locate
// on XCD b%8 (B/C panels of xc[b] shared across 8 heads -> L2-local).
__global__ __launch_bounds__(256) void ssd_stateA4(const ushort_t* __restrict__ xc,
        const float* __restrict__ dts, const float* __restrict__ alog,
        float* __restrict__ stbuf, float* __restrict__ acbuf) {
    int gidx = blockIdx.x;              // 1024
    int xcd = gidx & 7, sx = gidx >> 3; // per-XCD sequence 0..127
    int b = (sx >> 5) * 8 + xcd;        // 0..31, b%8 == xcd
    int h = (sx & 31) >> 2;             // 0..7
    int grp = sx & 3;                   // 0..3
    int bh = b * 8 + h;
    float Ah = -__expf(alog[h]);
    int tid = threadIdx.x;
    int q = tid >> 2, pb = (tid & 3) * 16;
    int w = tid >> 6, lane = tid & 63;
    int rr = lane & 15, quad = lane >> 4, qb = w * 16;

    __shared__ ushort_t Bt[64][68], Xt[64][68];
    __shared__ float dec_s[64];
    __shared__ float ad_sh;

    float T[4][4];
    #pragma unroll
    for (int t = 0; t < 4; t++)
        #pragma unroll
        for (int r2 = 0; r2 < 4; r2++) T[t][r2] = 0.f;

    // prefetch chunk grp*4
    ushort_t bv[16], xv[16];
    float d_pf = 0.f;
    {
        int chunk = grp * 4;
        int l0 = chunk * 64;
        const ushort_t* xrow = xc + (size_t)(b * 1024 + l0 + q) * 640;
        *(short8*)&bv[0] = *(const short8*)(xrow + 512 + pb);
        *(short8*)&bv[8] = *(const short8*)(xrow + 512 + pb + 8);
        *(short8*)&xv[0] = *(const short8*)(xrow + h * 64 + pb);
        *(short8*)&xv[8] = *(const short8*)(xrow + h * 64 + pb + 8);
        if (tid < 64)
            d_pf = dts[(size_t)(b * 1024 + l0 + tid) * 8 + h];
    }

    for (int c4 = 0; c4 < 4; c4++) {
        int chunk = grp * 4 + c4;
        size_t cidx = (size_t)bh * 16 + chunk;
        // P0: Xt transpose write + wave0 scalars (all from prefetched regs)
        #pragma unroll
        for (int j = 0; j < 16; j++) Xt[pb + j][q ^ xsw(pb + j)] = xv[j];
        if (tid < 64) {
            float d = d_pf;
            float a = d * Ah;
            #pragma unroll
            for (int off = 1; off < 64; off <<= 1) {
                float t = __shfl_up(a, off, 64);
                if (tid >= off) a += t;
            }
            acbuf[cidx * 64 + tid] = a;
            float tot = __shfl(a, 63, 64);
            dec_s[tid] = __expf(tot - a) * d;
            if (tid == 0) ad_sh = __expf(tot);
        }
        __syncthreads();    // b1: Xt + dec_s + ad_sh ready
        // P1: Bt from current bv (cvt_pk pairs), then prefetch next chunk
        {
            float dq = dec_s[q];
            #pragma unroll
            for (int j = 0; j < 16; j += 2) {
                uint_t u = cvt_pk2(b2f(bv[j]) * dq, b2f(bv[j + 1]) * dq);
                Bt[pb + j][q ^ xsw(pb + j)] = (ushort_t)u;
                Bt[pb + j + 1][q ^ xsw(pb + j + 1)] = (ushort_t)(u >> 16);
            }
        }
        if (c4 < 3) {
            int l0n = (chunk + 1) * 64;
            const ushort_t* xrow = xc + (size_t)(b * 1024 + l0n + q) * 640;
            *(short8*)&bv[0] = *(const short8*)(xrow + 512 + pb);
            *(short8*)&bv[8] = *(const short8*)(xrow + 512 + pb + 8);
            *(short8*)&xv[0] = *(const short8*)(xrow + h * 64 + pb);
            *(short8*)&xv[8] = *(const short8*)(xrow + h * 64 + pb + 8);
            if (tid < 64)
                d_pf = dts[(size_t)(b * 1024 + l0n + tid) * 8 + h];
        }
        __syncthreads();    // b2: Bt ready
        // P2: MFMA + T update
        f32x4 acc[4];
        #pragma unroll
        for (int t = 0; t < 4; t++) acc[t] = (f32x4){0.f, 0.f, 0.f, 0.f};
        #pragma unroll
        for (int ks = 0; ks < 2; ks++) {
            short8 a = *(const short8*)(&Bt[qb + rr][(ks * 32 + quad * 8) ^ xsw(qb + rr)]);
            #pragma unroll
            for (int t = 0; t < 4; t++) {
                short8 bb = *(const short8*)(&Xt[t * 16 + rr][(ks * 32 + quad * 8) ^ xsw(t * 16 + rr)]);
                acc[t] = __builtin_amdgcn_mfma_f32_16x16x32_bf16(a, bb, acc[t], 0, 0, 0);
            }
        }
        {
            float ad = ad_sh;
            #pragma unroll
            for (int t = 0; t < 4; t++)
                #pragma unroll
                for (int r2 = 0; r2 < 4; r2++)
                    T[t][r2] = ad * T[t][r2] + acc[t][r2];
        }
        __syncthreads();    // b3: tile reads done before next-iter overwrite
    }
    float* sb = stbuf + (size_t)(bh * 4 + grp) * 4096;  // [n][p] layout
    #pragma unroll
    for (int t = 0; t < 4; t++) {
        int p = t * 16 + rr;
        #pragma unroll
        for (int r2 = 0; r2 < 4; r2++)
            sb[(qb + quad * 4 + r2) * 64 + p] = T[t][r2];
    }
}

// ---------------- SSD C: per (b,h,group-of-4): y = Y_diag + Y_off + D*x ----------------
// 4 barriers/chunk; Gs aliases Bs (LDS 53.3KB -> 3 blocks/CU); next-chunk
// loads prefetched at P1 start; group prefix from stbuf in prologue.
// Tiles bank-swizzled via xsw(row). XCD-affinity: batch b on XCD b%8.
__global__ __launch_bounds__(256) void ssd_outBC4(const ushort_t* __restrict__ xc,
        const float* __restrict__ dts, const float* __restrict__ acbuf,
        const float* __restrict__ dsk, const float* __restrict__ stbuf,
        ushort_t* __restrict__ ybuf) {
    int gidx = blockIdx.x;              // 1024
    int xcd = gidx & 7, sx = gidx >> 3; // per-XCD sequence 0..127
    int b = (sx >> 5) * 8 + xcd;        // 0..31, b%8 == xcd
    int h = (sx & 31) >> 2;             // 0..7
    int grp = sx & 3;                   // 0..3
    int bh = b * 8 + h;
    float Dh = dsk[h];
    int tid = threadIdx.x;
    int q = tid >> 2, pb = (tid & 3) * 16;
    int w = tid >> 6, lane = tid & 63;
    int rr = lane & 15, quad = lane >> 4, qb = w * 16;

    __shared__ ushort_t Cs[64][68], Bs[64][68], Xt[64][68],
                        Bt[64][68], Shi[64][68], Slo[64][68];
    ushort_t (&Gs)[64][68] = Bs;        // alias: Bs dead after mm1, Gs born after
    __shared__ float acum_s[64], dtq_s[64], ea_s[64], dec_s[64];
    __shared__ float ad_sh;

    // running prefix state S, C/D layout: row nn=qb+quad*4+r2, col p=t*16+rr
    float S[4][4];
    #pragma unroll
    for (int t = 0; t < 4; t++)
        #pragma unroll
        for (int r2 = 0; r2 < 4; r2++) S[t][r2] = 0.f;
    for (int g = 0; g < grp; g++) {
        float Ag = 1.f;
        #pragma unroll
        for (int c = 0; c < 4; c++)
            Ag *= __expf(acbuf[((size_t)bh * 16 + g * 4 + c) * 64 + 63]);
        const float* s0 = stbuf + (size_t)(bh * 4 + g) * 4096;
        #pragma unroll
        for (int t = 0; t < 4; t++) {
            int p = t * 16 + rr;
            #pragma unroll
            for (int r2 = 0; r2 < 4; r2++)
                S[t][r2] = Ag * S[t][r2] + s0[(qb + quad * 4 + r2) * 64 + p];
        }
    }

    // prefetch chunk grp*4
    ushort_t bv[16], cv[16], xv[16];
    float a_pf = 0.f, d_pf = 0.f;
    {
        int chunk = grp * 4;
        int l0 = chunk * 64;
        const ushort_t* xrow = xc + (size_t)(b * 1024 + l0 + q) * 640;
        *(short8*)&bv[0] = *(const short8*)(xrow + 512 + pb);
        *(short8*)&bv[8] = *(const short8*)(xrow + 512 + pb + 8);
        *(short8*)&cv[0] = *(const short8*)(xrow + 576 + pb);
        *(short8*)&cv[8] = *(const short8*)(xrow + 576 + pb + 8);
        *(short8*)&xv[0] = *(const short8*)(xrow + h * 64 + pb);
        *(short8*)&xv[8] = *(const short8*)(xrow + h * 64 + pb + 8);
        if (tid < 64) {
            size_t cidx = (size_t)bh * 16 + chunk;
            a_pf = acbuf[cidx * 64 + tid];
            d_pf = dts[(size_t)(b * 1024 + l0 + tid) * 8 + h];
        }
    }

    int qq0 = qb + quad * 4;
    for (int c4 = 0; c4 < 4; c4++) {
        int chunk = grp * 4 + c4;
        int l0 = chunk * 64;
        // ---- P0: LDS tiles + scalars + Shi/Slo, all from regs ----
        {
            int swq = xsw(q);
            *(short8*)&Bs[q][pb ^ swq]       = *(const short8*)&bv[0];
            *(short8*)&Bs[q][(pb + 8) ^ swq] = *(const short8*)&bv[8];
            *(short8*)&Cs[q][pb ^ swq]       = *(const short8*)&cv[0];
            *(short8*)&Cs[q][(pb + 8) ^ swq] = *(const short8*)&cv[8];
        }
        #pragma unroll
        for (int j = 0; j < 16; j++) Xt[pb + j][q ^ xsw(pb + j)] = xv[j];
        if (tid < 64) {
            float a = a_pf;
            acum_s[tid] = a;
            ea_s[tid] = __expf(a);
            float d = d_pf;
            dtq_s[tid] = d;
            float tot = __shfl(a, 63, 64);
            dec_s[tid] = __expf(tot - a) * d;
            if (tid == 0) ad_sh = __expf(tot);
        }
        // Shi/Slo from S regs (A-operand layout [p][n]); cvt_pk + b64 stores
        #pragma unroll
        for (int t = 0; t < 4; t++) {
            int p = t * 16 + rr;
            uint_t h01 = cvt_pk2(S[t][0], S[t][1]);
            uint_t h23 = cvt_pk2(S[t][2], S[t][3]);
            float l0r = S[t][0] - b2f((ushort_t)h01);
            float l1r = S[t][1] - b2f((ushort_t)(h01 >> 16));
            float l2r = S[t][2] - b2f((ushort_t)h23);
            float l3r = S[t][3] - b2f((ushort_t)(h23 >> 16));
            uint_t lo01 = cvt_pk2(l0r, l1r);
            uint_t lo23 = cvt_pk2(l2r, l3r);
            int swp = xsw(p);
            *(uint2*)&Shi[p][qq0 ^ swp] = make_uint2(h01, h23);
            *(uint2*)&Slo[p][qq0 ^ swp] = make_uint2(lo01, lo23);
        }
        __syncthreads();    // b1: tiles + state + scalars ready

        // ---- P1: Bt (cvt_pk), prefetch next chunk, mm1 -> packed regs ----
        {
            float dq = dec_s[q];
            #pragma unroll
            for (int j = 0; j < 16; j += 2) {
                uint_t u = cvt_pk2(b2f(bv[j]) * dq, b2f(bv[j + 1]) * dq);
                Bt[pb + j][q ^ xsw(pb + j)] = (ushort_t)u;
                Bt[pb + j + 1][q ^ xsw(pb + j + 1)] = (ushort_t)(u >> 16);
            }
        }
        if (c4 < 3) {
            int l0n = (chunk + 1) * 64;
            const ushort_t* xrow = xc + (size_t)(b * 1024 + l0n + q) * 640;
            *(short8*)&bv[0] = *(const short8*)(xrow + 512 + pb);
            *(short8*)&bv[8] = *(const short8*)(xrow + 512 + pb + 8);
            *(short8*)&cv[0] = *(const short8*)(xrow + 576 + pb);
            *(short8*)&cv[8] = *(const short8*)(xrow + 576 + pb + 8);
            *(short8*)&xv[0] = *(const short8*)(xrow + h * 64 + pb);
            *(short8*)&xv[8] = *(const short8*)(xrow + h * 64 + pb + 8);
            if (tid < 64) {
                size_t cidxn = (size_t)bh * 16 + chunk + 1;
                a_pf = acbuf[cidxn * 64 + tid];
                d_pf = dts[(size_t)(b * 1024 + l0n + tid) * 8 + h];
            }
        }
        // mm1: G = C.B^T masked -> packed bf16 in regs
        uint_t gp01[4], gp23[4];
        {
            f32x4 g[4];
            #pragma unroll
            for (int t = 0; t < 4; t++) g[t] = (f32x4){0.f, 0.f, 0.f, 0.f};
            #pragma unroll
            for (int ks = 0; ks < 2; ks++) {
                short8 a = *(const short8*)(&Cs[qb + rr][(ks * 32 + quad * 8) ^ xsw(qb + rr)]);
                #pragma unroll
                for (int t = 0; t < 4; t++) {
                    short8 bb = *(const short8*)(&Bs[t * 16 + rr][(ks * 32 + quad * 8) ^ xsw(t * 16 + rr)]);
                    g[t] = __builtin_amdgcn_mfma_f32_16x16x32_bf16(a, bb, g[t], 0, 0, 0);
                }
            }
            #pragma unroll
            for (int t = 0; t < 4; t++) {
                int s = t * 16 + rr;
                float as = acum_s[s], dss = dtq_s[s];
                float vv[4];
                #pragma unroll
                for (int r2 = 0; r2 < 4; r2++) {
                    int qq = qq0 + r2;
                    vv[r2] = (s <= qq) ? g[t][r2] * __expf(acum_s[qq] - as) * dss : 0.f;
                }
                gp01[t] = cvt_pk2(vv[0], vv[1]);
                gp23[t] = cvt_pk2(vv[2], vv[3]);
            }
        }
        __syncthreads();    // b2a: all mm1 reads of Bs complete
        #pragma unroll
        for (int t = 0; t < 4; t++) {
            int s = t * 16 + rr;
            Gs[qq0][s ^ xsw(qq0)]         = (ushort_t)gp01[t];
            Gs[qq0 + 1][s ^ xsw(qq0 + 1)] = (ushort_t)(gp01[t] >> 16);
            Gs[qq0 + 2][s ^ xsw(qq0 + 2)] = (ushort_t)gp23[t];
            Gs[qq0 + 3][s ^ xsw(qq0 + 3)] = (ushort_t)(gp23[t] >> 16);
        }
        __syncthreads();    // b2b: Gs ready

        // ---- P2: mm2 (Y_diag + Y_off) + state update + y write ----
        f32x4 aD[4], aO[4];
        #pragma unroll
        for (int t = 0; t < 4; t++) { aD[t] = (f32x4){0.f,0.f,0.f,0.f}; aO[t] = (f32x4){0.f,0.f,0.f,0.f}; }
        #pragma unroll
        for (int ks = 0; ks < 2; ks++) {
            short8 ga = *(const short8*)(&Gs[qb + rr][(ks * 32 + quad * 8) ^ xsw(qb + rr)]);
            short8 ca = *(const short8*)(&Cs[qb + rr][(ks * 32 + quad * 8) ^ xsw(qb + rr)]);
            #pragma unroll
            for (int t = 0; t < 4; t++) {
                int rowt = t * 16 + rr;
                int swt = xsw(rowt);
                short8 xb = *(const short8*)(&Xt[rowt][(ks * 32 + quad * 8) ^ swt]);
                short8 sh = *(const short8*)(&Shi[rowt][(ks * 32 + quad * 8) ^ swt]);
                short8 sl = *(const short8*)(&Slo[rowt][(ks * 32 + quad * 8) ^ swt]);
                aD[t] = __builtin_amdgcn_mfma_f32_16x16x32_bf16(ga, xb, aD[t], 0, 0, 0);
                aO[t] = __builtin_amdgcn_mfma_f32_16x16x32_bf16(ca, sh, aO[t], 0, 0, 0);
                aO[t] = __builtin_amdgcn_mfma_f32_16x16x32_bf16(ca, sl, aO[t], 0, 0, 0);
            }
        }
        // state update MFMA: S = ad*S + Bt^T @ X
        {
            f32x4 acc[4];
            #pragma unroll
            for (int t = 0; t < 4; t++) acc[t] = (f32x4){0.f, 0.f, 0.f, 0.f};
            #pragma unroll
            for (int ks = 0; ks < 2; ks++) {
                short8 a = *(const short8*)(&Bt[qb + rr][(ks * 32 + quad * 8) ^ xsw(qb + rr)]);
                #pragma unroll
                for (int t = 0; t < 4; t++) {
                    short8 bb = *(const short8*)(&Xt[t * 16 + rr][(ks * 32 + quad * 8) ^ xsw(t * 16 + rr)]);
                    acc[t] = __builtin_amdgcn_mfma_f32_16x16x32_bf16(a, bb, acc[t], 0, 0, 0);
                }
            }
            #pragma unroll
            for (int t = 0; t < 4; t++) {
                int p = t * 16 + rr;
                int swp = xsw(p);
                float yv[4];
                #pragma unroll
                for (int r2 = 0; r2 < 4; r2++) {
                    int qq = qq0 + r2;
                    yv[r2] = aD[t][r2] + ea_s[qq] * aO[t][r2] + Dh * b2f(Xt[p][qq ^ swp]);
                }
                uint_t u01 = cvt_pk2(yv[0], yv[1]);
                uint_t u23 = cvt_pk2(yv[2], yv[3]);
                size_t base = (size_t)(b * 1024 + l0 + qq0) * 512 + h * 64 + p;
                ybuf[base]        = (ushort_t)u01;
                ybuf[base + 512]  = (ushort_t)(u01 >> 16);
                ybuf[base + 1024] = (ushort_t)u23;
                ybuf[base + 1536] = (ushort_t)(u23 >> 16);
            }
            float ad = ad_sh;
            #pragma unroll
            for (int t = 0; t < 4; t++)
                #pragma unroll
                for (int r2 = 0; r2 < 4; r2++)
                    S[t][r2] = ad * S[t][r2] + acc[t][r2];
        }
        __syncthreads();    // b3: all tile reads done before next P0 overwrite
    }
}

// ---------------- head ----------------
__global__ __launch_bounds__(256) void head_kernel(const float* __restrict__ h,
        const float* __restrict__ hw, const float* __restrict__ stdb,
        const float* __restrict__ meanb, float* __restrict__ out) {
    int blk = blockIdx.x;       // b*192 + t
    int b = blk / 192, t = blk - b * 192;
    int l = 832 + t;
    int tid = threadIdx.x;
    __shared__ float hr[256];
    hr[tid] = h[(size_t)(b * 1024 + l) * 256 + tid];
    __syncthreads();
    if (tid < 21) {
        float acc = 0.f;
        for (int k = 0; k < 256; k++) acc += hr[k] * hw[tid * 256 + k];
        out[(size_t)blk * 21 + tid] = acc * stdb[b * 21 + tid] + meanb[b * 21 + tid];
    }
}

extern "C" void kernel_launch(void* const* d_in, const int* in_sizes, int n_in,
                              void* d_out, int out_size, void* d_ws, size_t ws_size,
                              hipStream_t stream) {
    const float* x_enc  = (const float*)d_in[0];
    const float* x_mark = (const float*)d_in[1];
    const float* tokw   = (const float*)d_in[4];
    const float* tembw  = (const float*)d_in[5];
    const float* ln_g   = (const float*)d_in[6];
    const float* ln_b   = (const float*)d_in[7];
    const float* ipw    = (const float*)d_in[8];
    const float* cw     = (const float*)d_in[9];
    const float* cb     = (const float*)d_in[10];
    const float* dtb    = (const float*)d_in[11];
    const float* alog   = (const float*)d_in[12];
    const float* dsk    = (const float*)d_in[13];
    const float* gw     = (const float*)d_in[14];
    const float* opw    = (const float*)d_in[15];
    const float* hw     = (const float*)d_in[16];
    float* out = (float*)d_out;

    char* w = (char*)d_ws;
    size_t off = 0;
    auto alloc = [&](size_t bytes) -> void* {
        void* p = w + off;
        off += (bytes + 255) & ~(size_t)255;
        return p;
    };
    float* meanb  = (float*)alloc(672 * 4);
    float* stdb   = (float*)alloc(672 * 4);
    float* rstdb  = (float*)alloc(672 * 4);
    float* dts    = (float*)alloc((size_t)262144 * 4);            // 1.05 MB
    float* pebuf  = (float*)alloc((size_t)262144 * 4);            // 1.05 MB
    float* cwt    = (float*)alloc((size_t)10240 * 4);             // 40 KB
    float* hbuf   = (float*)alloc((size_t)8388608 * 4);           // 33.55 MB
    ushort_t* hbf = (ushort_t*)alloc((size_t)8388608 * 2);        // 16.78 MB
    ushort_t* zbuf= (ushort_t*)alloc((size_t)32768 * 512 * 2);    // 33.55 MB
    ushort_t* xc  = (ushort_t*)alloc((size_t)32768 * 640 * 2);    // 41.94 MB
    char* R       = (char*)alloc((size_t)71303168);               // 71.30 MB union
    ushort_t* ybuf= (ushort_t*)alloc((size_t)32768 * 512 * 2);    // 33.55 MB
    ushort_t* wipb= (ushort_t*)alloc((size_t)4 * 1280 * 256 * 2); // 2.62 MB
    ushort_t* wopb= (ushort_t*)alloc((size_t)4 * 256 * 512 * 2);  // 1.05 MB
    // region R aliases: xbuf (gemm_ip out) dies after conv+dt; stbuf/acbuf take over
    ushort_t* xbuf = (ushort_t*)R;                        // 32768 x 704 bf16 = 46.14 MB
    float* stbuf   = (float*)R;                           // 1024 x 4096 fp32 = 16.78 MB (group partials)
    float* acbuf   = (float*)(R + 67108864);              // 256*16*64 fp32 = 4.19 MB
    (void)ws_size; (void)in_sizes; (void)n_in; (void)out_size;
    // total ~236.5 MB

    stats_kernel<<<672, 256, 0, stream>>>(x_enc, meanb, stdb, rstdb);
    pe_kernel<<<1024, 256, 0, stream>>>(pebuf);
    cvt_pad_ip<<<5120, 256, 0, stream>>>(ipw, wipb);
    cvt_wop<<<2048, 256, 0, stream>>>(opw, gw, wopb);     // fold gnorm_w into Wo
    cvt_convw<<<40, 256, 0, stream>>>(cw, cwt);
    embed3_kernel<<<512, 256, 0, stream>>>(x_enc, x_mark, tokw, tembw, pebuf,
                                           meanb, rstdb, hbuf, hbf);

    for (int layer = 0; layer < 4; layer++) {
        // in_proj: 2560 blocks, XCD-affinity map, BK=64; reads hbf
        gemm_ip<<<2560, 256, 0, stream>>>(hbf, wipb + (size_t)layer * 1280 * 256,
                                          zbuf, xbuf);
        // conv (2560 blocks) + dt (128 blocks), block-uniform split
        conv_kernel<<<2688, 256, 0, stream>>>(xbuf, cwt + layer * 2560,
                                              cb + layer * 640, dtb + layer * 8,
                                              xc, dts);
        // xbuf now dead -> stbuf/acbuf overwrite region R; XCD-affinity grids
        ssd_stateA4<<<1024, 256, 0, stream>>>(xc, dts, alog + layer * 8, stbuf, acbuf);
        // outBC4 computes its own group prefix from stbuf (scan folded in)
        ssd_outBC4<<<1024, 256, 0, stream>>>(xc, dts, acbuf, dsk + layer * 8,
                                             stbuf, ybuf);
        // fused gate + out_proj + residual + LN (M=32, 1024 blocks, 4/CU)
        gemm_og<<<1024, 256, 0, stream>>>(ybuf, zbuf,
                                          wopb + (size_t)layer * 256 * 512,
                                          hbuf, hbf,
                                          ln_g + layer * 256, ln_b + layer * 256);
    }

    head_kernel<<<6144, 256, 0, stream>>>(hbuf, hw, stdb, meanb, out);
}